// Round 4
// baseline (1662.476 us; speedup 1.0000x reference)
//
#include <hip/hip_runtime.h>
#include <math.h>

// GCN 2-layer, N=500k, E=16M, F 5->5->8.
// R4: R3 bucket structure + (a) fp16 feature tables (16B rows, 8 MB/table,
//     ~2x better per-XCD L2 hit rate on random gathers), (b) non-temporal
//     loads/stores for all one-shot streams so they don't evict the table.
// All atomics stay in LDS. Fallback to R1 atomic-scatter if ws too small.

#define FIN 5
#define FHID 5
#define FOUT 8
#define RB 256       // nodes per bucket (== block size)
#define EPB 16384    // edges per binning block
#define NBUCK_MAX 2048

typedef _Float16 half8 __attribute__((ext_vector_type(8)));

// ---------- binning ----------

__global__ void k_binhist(const int* __restrict__ dst, int* __restrict__ cnt,
                          int e, int nbuck, int nblkE) {
    __shared__ int hist[NBUCK_MAX];
    int tx = threadIdx.x, blk = blockIdx.x;
    for (int b = tx; b < nbuck; b += 256) hist[b] = 0;
    __syncthreads();
    size_t base = (size_t)blk * EPB;
    for (int k = 0; k < EPB; k += 256) {
        size_t i = base + k + tx;
        if (i < (size_t)e) {
            int d = __builtin_nontemporal_load(&dst[i]);
            atomicAdd(&hist[d >> 8], 1);
        }
    }
    __syncthreads();
    for (int b = tx; b < nbuck; b += 256) cnt[(size_t)b * nblkE + blk] = hist[b];
}

__global__ void k_scan1(const int* __restrict__ t, int* __restrict__ scn,
                        int* __restrict__ partial, int n) {
    __shared__ int sh[256];
    int tx = threadIdx.x;
    int i = blockIdx.x * 256 + tx;
    int v = (i < n) ? t[i] : 0;
    sh[tx] = v;
    __syncthreads();
    for (int off = 1; off < 256; off <<= 1) {
        int add = (tx >= off) ? sh[tx - off] : 0;
        __syncthreads();
        sh[tx] += add;
        __syncthreads();
    }
    if (i < n) scn[i] = sh[tx] - v;
    if (tx == 255) partial[blockIdx.x] = sh[255];
}

__global__ void k_scan2(int* __restrict__ partial, int nb) {
    __shared__ int sh[256];
    __shared__ int carry;
    int tx = threadIdx.x;
    if (tx == 0) carry = 0;
    __syncthreads();
    for (int base = 0; base < nb; base += 256) {
        int i = base + tx;
        int v = (i < nb) ? partial[i] : 0;
        int c0 = carry;
        sh[tx] = v;
        __syncthreads();
        for (int off = 1; off < 256; off <<= 1) {
            int add = (tx >= off) ? sh[tx - off] : 0;
            __syncthreads();
            sh[tx] += add;
            __syncthreads();
        }
        if (i < nb) partial[i] = c0 + sh[tx] - v;
        __syncthreads();
        if (tx == 0) carry = c0 + sh[255];
        __syncthreads();
    }
}

__global__ void k_binscatter(const int* __restrict__ src, const int* __restrict__ dst,
                             const int* __restrict__ scn, const int* __restrict__ part,
                             unsigned int* __restrict__ binned,
                             int e, int nbuck, int nblkE) {
    __shared__ int cur[NBUCK_MAX];
    int tx = threadIdx.x, blk = blockIdx.x;
    for (int b = tx; b < nbuck; b += 256) {
        size_t idx = (size_t)b * nblkE + blk;
        cur[b] = scn[idx] + part[idx >> 8];
    }
    __syncthreads();
    size_t base = (size_t)blk * EPB;
    for (int k = 0; k < EPB; k += 256) {
        size_t i = base + k + tx;
        if (i < (size_t)e) {
            int d = __builtin_nontemporal_load(&dst[i]);
            int s = __builtin_nontemporal_load(&src[i]);
            int pos = atomicAdd(&cur[d >> 8], 1);
            unsigned int pk = ((unsigned int)(d & (RB - 1)) << 24) | (unsigned int)s;
            __builtin_nontemporal_store(pk, &binned[pos]);
        }
    }
}

// ---------- per-bucket passes ----------

__device__ __forceinline__ void bucket_range(const int* __restrict__ scn,
                                             const int* __restrict__ part,
                                             int b, int nbuck, int nblkE, int e,
                                             int& start, int& end) {
    size_t i0 = (size_t)b * nblkE;
    start = scn[i0] + part[i0 >> 8];
    if (b + 1 < nbuck) {
        size_t i1 = (size_t)(b + 1) * nblkE;
        end = scn[i1] + part[i1 >> 8];
    } else {
        end = e;
    }
}

// degree (LDS count) -> dinv, g1 = fp16(x * dinv)
__global__ void k_deg_g(const unsigned int* __restrict__ binned,
                        const int* __restrict__ scn, const int* __restrict__ part,
                        const float* __restrict__ x, float* __restrict__ dinv,
                        half8* __restrict__ g1, int n, int e, int nbuck, int nblkE) {
    __shared__ int cnt[RB];
    int tx = threadIdx.x, b = blockIdx.x;
    cnt[tx] = 0;
    __syncthreads();
    int start, end;
    bucket_range(scn, part, b, nbuck, nblkE, e, start, end);
    for (int i = start + tx; i < end; i += 256) {
        unsigned int p = __builtin_nontemporal_load(&binned[i]);
        atomicAdd(&cnt[p >> 24], 1);
    }
    __syncthreads();
    int node = b * RB + tx;
    if (node < n) {
        float d = rsqrtf((float)(cnt[tx] + 1));  // +1 self-loop
        dinv[node] = d;
        const float* xp = x + (size_t)node * FIN;
        half8 row = {};
#pragma unroll
        for (int f = 0; f < FIN; ++f) row[f] = (_Float16)(xp[f] * d);
        g1[node] = row;
    }
}

// layer 1: LDS-accumulate gathered fp16 g1, fused W1+relu, g2 = fp16(h*dinv)
__global__ void k_bagg1(const unsigned int* __restrict__ binned,
                        const int* __restrict__ scn, const int* __restrict__ part,
                        const half8* __restrict__ g1, const float* __restrict__ dinv,
                        const float* __restrict__ W1, const float* __restrict__ b1,
                        half8* __restrict__ g2, int n, int e, int nbuck, int nblkE) {
    __shared__ float acc[FIN * RB];  // feature-major
    int tx = threadIdx.x, b = blockIdx.x;
#pragma unroll
    for (int f = 0; f < FIN; ++f) acc[f * RB + tx] = 0.0f;
    __syncthreads();
    int start, end;
    bucket_range(scn, part, b, nbuck, nblkE, e, start, end);
    for (int i = start + tx; i < end; i += 256) {
        unsigned int p = __builtin_nontemporal_load(&binned[i]);
        int s = (int)(p & 0xFFFFFF);
        int dl = (int)(p >> 24);
        half8 hv = g1[s];                 // cached gather (the hot table)
        atomicAdd(&acc[dl],          (float)hv[0]);
        atomicAdd(&acc[RB + dl],     (float)hv[1]);
        atomicAdd(&acc[2 * RB + dl], (float)hv[2]);
        atomicAdd(&acc[3 * RB + dl], (float)hv[3]);
        atomicAdd(&acc[4 * RB + dl], (float)hv[4]);
    }
    __syncthreads();
    int node = b * RB + tx;
    if (node >= n) return;
    float d = dinv[node];
    half8 gi = g1[node];
    float v[FIN];
#pragma unroll
    for (int f = 0; f < FIN; ++f) v[f] = (acc[f * RB + tx] + (float)gi[f]) * d;
    half8 go = {};
#pragma unroll
    for (int j = 0; j < FHID; ++j) {
        float s = b1[j];
#pragma unroll
        for (int k = 0; k < FIN; ++k) s = fmaf(v[k], W1[k * FHID + j], s);
        go[j] = (_Float16)(fmaxf(s, 0.0f) * d);  // relu, pre-scaled for layer 2
    }
    g2[node] = go;
}

// layer 2: LDS-accumulate gathered fp16 g2, fused W2 + log_softmax
__global__ void k_bagg2(const unsigned int* __restrict__ binned,
                        const int* __restrict__ scn, const int* __restrict__ part,
                        const half8* __restrict__ g2, const float* __restrict__ dinv,
                        const float* __restrict__ W2, const float* __restrict__ b2,
                        float* __restrict__ out, int n, int e, int nbuck, int nblkE) {
    __shared__ float acc[FHID * RB];
    int tx = threadIdx.x, b = blockIdx.x;
#pragma unroll
    for (int f = 0; f < FHID; ++f) acc[f * RB + tx] = 0.0f;
    __syncthreads();
    int start, end;
    bucket_range(scn, part, b, nbuck, nblkE, e, start, end);
    for (int i = start + tx; i < end; i += 256) {
        unsigned int p = __builtin_nontemporal_load(&binned[i]);
        int s = (int)(p & 0xFFFFFF);
        int dl = (int)(p >> 24);
        half8 hv = g2[s];
        atomicAdd(&acc[dl],          (float)hv[0]);
        atomicAdd(&acc[RB + dl],     (float)hv[1]);
        atomicAdd(&acc[2 * RB + dl], (float)hv[2]);
        atomicAdd(&acc[3 * RB + dl], (float)hv[3]);
        atomicAdd(&acc[4 * RB + dl], (float)hv[4]);
    }
    __syncthreads();
    int node = b * RB + tx;
    if (node >= n) return;
    float d = dinv[node];
    half8 gi = g2[node];
    float v[FHID];
#pragma unroll
    for (int f = 0; f < FHID; ++f) v[f] = (acc[f * RB + tx] + (float)gi[f]) * d;
    float o[FOUT];
    float m = -1e30f;
#pragma unroll
    for (int j = 0; j < FOUT; ++j) {
        float s = b2[j];
#pragma unroll
        for (int k = 0; k < FHID; ++k) s = fmaf(v[k], W2[k * FOUT + j], s);
        o[j] = s;
        m = fmaxf(m, s);
    }
    float ssum = 0.0f;
#pragma unroll
    for (int j = 0; j < FOUT; ++j) ssum += expf(o[j] - m);
    float lse = m + logf(ssum);
    float* op = out + (size_t)node * FOUT;
#pragma unroll
    for (int j = 0; j < FOUT; ++j) op[j] = o[j] - lse;
}

// ---------- fallback (R1) ----------

__global__ void f_init_deg(float* __restrict__ deg, int n) {
    int i = blockIdx.x * blockDim.x + threadIdx.x;
    if (i < n) deg[i] = 1.0f;
}
__global__ void f_count_deg(const int* __restrict__ dst, float* __restrict__ deg, int e) {
    int i = blockIdx.x * blockDim.x + threadIdx.x;
    if (i < e) atomicAdd(&deg[dst[i]], 1.0f);
}
__global__ void f_finish_deg_g1(const float* __restrict__ x, float* __restrict__ dinv,
                                float* __restrict__ g1, int n) {
    int i = blockIdx.x * blockDim.x + threadIdx.x;
    if (i >= n) return;
    float d = rsqrtf(dinv[i]);
    dinv[i] = d;
#pragma unroll
    for (int f = 0; f < FIN; ++f) g1[(size_t)i * FIN + f] = x[(size_t)i * FIN + f] * d;
}
__global__ void f_scatter5(const int* __restrict__ src, const int* __restrict__ dst,
                           const float* __restrict__ g, float* __restrict__ acc, int e) {
    int i = blockIdx.x * blockDim.x + threadIdx.x;
    if (i >= e) return;
    int s = src[i], d = dst[i];
    float* a = acc + (size_t)d * 5;
    const float* gp = g + (size_t)s * 5;
    atomicAdd(a + 0, gp[0]);
    atomicAdd(a + 1, gp[1]);
    atomicAdd(a + 2, gp[2]);
    atomicAdd(a + 3, gp[3]);
    atomicAdd(a + 4, gp[4]);
}
__global__ void f_update1(const float* __restrict__ dinv, float* __restrict__ g,
                          float* __restrict__ acc, const float* __restrict__ W1,
                          const float* __restrict__ b1, int n) {
    int i = blockIdx.x * blockDim.x + threadIdx.x;
    if (i >= n) return;
    float d = dinv[i];
    float v[FIN];
#pragma unroll
    for (int f = 0; f < FIN; ++f) {
        size_t idx = (size_t)i * FIN + f;
        v[f] = (acc[idx] + g[idx]) * d;
        acc[idx] = 0.0f;
    }
#pragma unroll
    for (int j = 0; j < FHID; ++j) {
        float s = b1[j];
#pragma unroll
        for (int k = 0; k < FIN; ++k) s += v[k] * W1[k * FHID + j];
        g[(size_t)i * FHID + j] = fmaxf(s, 0.0f) * d;
    }
}
__global__ void f_update2(const float* __restrict__ dinv, const float* __restrict__ g,
                          const float* __restrict__ acc, const float* __restrict__ W2,
                          const float* __restrict__ b2, float* __restrict__ out, int n) {
    int i = blockIdx.x * blockDim.x + threadIdx.x;
    if (i >= n) return;
    float d = dinv[i];
    float v[FHID];
#pragma unroll
    for (int f = 0; f < FHID; ++f) v[f] = (acc[(size_t)i * FHID + f] + g[(size_t)i * FHID + f]) * d;
    float o[FOUT];
    float m = -1e30f;
#pragma unroll
    for (int j = 0; j < FOUT; ++j) {
        float s = b2[j];
#pragma unroll
        for (int k = 0; k < FHID; ++k) s += v[k] * W2[k * FOUT + j];
        o[j] = s;
        m = fmaxf(m, s);
    }
    float ssum = 0.0f;
#pragma unroll
    for (int j = 0; j < FOUT; ++j) ssum += expf(o[j] - m);
    float lse = m + logf(ssum);
#pragma unroll
    for (int j = 0; j < FOUT; ++j) out[(size_t)i * FOUT + j] = o[j] - lse;
}

// ---------- launcher ----------

extern "C" void kernel_launch(void* const* d_in, const int* in_sizes, int n_in,
                              void* d_out, int out_size, void* d_ws, size_t ws_size,
                              hipStream_t stream) {
    const float* x  = (const float*)d_in[0];
    const int*   ei = (const int*)d_in[1];
    const float* W1 = (const float*)d_in[2];
    const float* b1 = (const float*)d_in[3];
    const float* W2 = (const float*)d_in[4];
    const float* b2 = (const float*)d_in[5];

    const int n = in_sizes[0] / FIN;   // 500,000
    const int e = in_sizes[1] / 2;     // 16,000,000
    const int* src = ei;
    const int* dst = ei + e;

    const int nbuck = (n + RB - 1) / RB;          // 1954
    const int nblkE = (e + EPB - 1) / EPB;        // 977
    const size_t m = (size_t)nbuck * nblkE;       // ~1.9M
    const int nsb = (int)((m + 255) / 256);

    size_t off = 0;
    auto alloc = [&](size_t bytes) { size_t o = off; off = (off + bytes + 15) & ~(size_t)15; return o; };
    int*          cnt    = (int*)((char*)d_ws + alloc(m * 4));
    int*          scn    = (int*)((char*)d_ws + alloc(m * 4));
    int*          part   = (int*)((char*)d_ws + alloc((size_t)nsb * 4));
    float*        dinv   = (float*)((char*)d_ws + alloc((size_t)n * 4));
    half8*        g1     = (half8*)((char*)d_ws + alloc((size_t)n * 16));
    half8*        g2     = (half8*)((char*)d_ws + alloc((size_t)n * 16));
    unsigned int* binned = (unsigned int*)((char*)d_ws + alloc((size_t)e * 4));
    const size_t need = off;

    const int B = 256;

    if (ws_size >= need && n <= (1 << 24) && nbuck <= NBUCK_MAX) {
        k_binhist<<<nblkE, B, 0, stream>>>(dst, cnt, e, nbuck, nblkE);
        k_scan1<<<nsb, B, 0, stream>>>(cnt, scn, part, (int)m);
        k_scan2<<<1, B, 0, stream>>>(part, nsb);
        k_binscatter<<<nblkE, B, 0, stream>>>(src, dst, scn, part, binned, e, nbuck, nblkE);
        k_deg_g<<<nbuck, B, 0, stream>>>(binned, scn, part, x, dinv, g1, n, e, nbuck, nblkE);
        k_bagg1<<<nbuck, B, 0, stream>>>(binned, scn, part, g1, dinv, W1, b1, g2, n, e, nbuck, nblkE);
        k_bagg2<<<nbuck, B, 0, stream>>>(binned, scn, part, g2, dinv, W2, b2, (float*)d_out, n, e, nbuck, nblkE);
    } else {
        const int gn = (n + B - 1) / B;
        const int ge = (e + B - 1) / B;
        float* fdinv = (float*)d_ws;
        float* fg    = fdinv + n;
        float* facc  = fg + (size_t)5 * n;
        hipMemsetAsync(facc, 0, (size_t)5 * n * sizeof(float), stream);
        f_init_deg<<<gn, B, 0, stream>>>(fdinv, n);
        f_count_deg<<<ge, B, 0, stream>>>(dst, fdinv, e);
        f_finish_deg_g1<<<gn, B, 0, stream>>>(x, fdinv, fg, n);
        f_scatter5<<<ge, B, 0, stream>>>(src, dst, fg, facc, e);
        f_update1<<<gn, B, 0, stream>>>(fdinv, fg, facc, W1, b1, n);
        f_scatter5<<<ge, B, 0, stream>>>(src, dst, fg, facc, e);
        f_update2<<<gn, B, 0, stream>>>(fdinv, fg, facc, W2, b2, (float*)d_out, n);
    }
}

// Round 5
// 1357.405 us; speedup vs baseline: 1.2247x; 1.2247x over previous
//
#include <hip/hip_runtime.h>
#include <math.h>

// GCN 2-layer, N=500k, E=16M, F 5->5->8.
// R5: bucket binning (EPB=32768 for 2x longer scatter runs), PLAIN stores in
//     binscatter (R4's NT store caused 16x write amplification), fp16 feature
//     tables (8 MB), NT loads on one-shot streams, and per-bucket slice-sort
//     by src>>14 fused into the degree pass so bagg gathers walk the table
//     slice-by-slice (L2-resident working set). All atomics in LDS.

#define FIN 5
#define FHID 5
#define FOUT 8
#define RB 256        // nodes per bucket (== block size)
#define EPB 32768     // edges per binning block
#define NBUCK_MAX 2048
#define SLICE_SHIFT 14
#define NSLICE 64
#define SORT_CAP 12288   // max staged edges per bucket (48 KB LDS)

typedef _Float16 half8 __attribute__((ext_vector_type(8)));

// ---------- binning ----------

__global__ void k_binhist(const int* __restrict__ dst, int* __restrict__ cnt,
                          int e, int nbuck, int nblkE) {
    __shared__ int hist[NBUCK_MAX];
    int tx = threadIdx.x, blk = blockIdx.x;
    for (int b = tx; b < nbuck; b += 256) hist[b] = 0;
    __syncthreads();
    size_t base = (size_t)blk * EPB;
    for (int k = 0; k < EPB; k += 256) {
        size_t i = base + k + tx;
        if (i < (size_t)e) {
            int d = __builtin_nontemporal_load(&dst[i]);
            atomicAdd(&hist[d >> 8], 1);
        }
    }
    __syncthreads();
    for (int b = tx; b < nbuck; b += 256) cnt[(size_t)b * nblkE + blk] = hist[b];
}

__global__ void k_scan1(const int* __restrict__ t, int* __restrict__ scn,
                        int* __restrict__ partial, int n) {
    __shared__ int sh[256];
    int tx = threadIdx.x;
    int i = blockIdx.x * 256 + tx;
    int v = (i < n) ? t[i] : 0;
    sh[tx] = v;
    __syncthreads();
    for (int off = 1; off < 256; off <<= 1) {
        int add = (tx >= off) ? sh[tx - off] : 0;
        __syncthreads();
        sh[tx] += add;
        __syncthreads();
    }
    if (i < n) scn[i] = sh[tx] - v;
    if (tx == 255) partial[blockIdx.x] = sh[255];
}

__global__ void k_scan2(int* __restrict__ partial, int nb) {
    __shared__ int sh[256];
    __shared__ int carry;
    int tx = threadIdx.x;
    if (tx == 0) carry = 0;
    __syncthreads();
    for (int base = 0; base < nb; base += 256) {
        int i = base + tx;
        int v = (i < nb) ? partial[i] : 0;
        int c0 = carry;
        sh[tx] = v;
        __syncthreads();
        for (int off = 1; off < 256; off <<= 1) {
            int add = (tx >= off) ? sh[tx - off] : 0;
            __syncthreads();
            sh[tx] += add;
            __syncthreads();
        }
        if (i < nb) partial[i] = c0 + sh[tx] - v;
        __syncthreads();
        if (tx == 0) carry = c0 + sh[255];
        __syncthreads();
    }
}

__global__ void k_binscatter(const int* __restrict__ src, const int* __restrict__ dst,
                             const int* __restrict__ scn, const int* __restrict__ part,
                             unsigned int* __restrict__ binned,
                             int e, int nbuck, int nblkE) {
    __shared__ int cur[NBUCK_MAX];
    int tx = threadIdx.x, blk = blockIdx.x;
    for (int b = tx; b < nbuck; b += 256) {
        size_t idx = (size_t)b * nblkE + blk;
        cur[b] = scn[idx] + part[idx >> 8];
    }
    __syncthreads();
    size_t base = (size_t)blk * EPB;
    for (int k = 0; k < EPB; k += 256) {
        size_t i = base + k + tx;
        if (i < (size_t)e) {
            int d = __builtin_nontemporal_load(&dst[i]);
            int s = __builtin_nontemporal_load(&src[i]);
            int pos = atomicAdd(&cur[d >> 8], 1);
            // plain store: contiguous runs per (block,bucket) coalesce in L2
            binned[pos] = ((unsigned int)(d & (RB - 1)) << 24) | (unsigned int)s;
        }
    }
}

// ---------- per-bucket passes ----------

__device__ __forceinline__ void bucket_range(const int* __restrict__ scn,
                                             const int* __restrict__ part,
                                             int b, int nbuck, int nblkE, int e,
                                             int& start, int& end) {
    size_t i0 = (size_t)b * nblkE;
    start = scn[i0] + part[i0 >> 8];
    if (b + 1 < nbuck) {
        size_t i1 = (size_t)(b + 1) * nblkE;
        end = scn[i1] + part[i1 >> 8];
    } else {
        end = e;
    }
}

// degree -> dinv, g1 = fp16(x*dinv), AND in-place slice-sort of the bucket's
// edge segment by src>>SLICE_SHIFT (skipped for oversized buckets: order is a
// perf hint only).
__global__ void k_deg_sort(unsigned int* __restrict__ binned,
                           const int* __restrict__ scn, const int* __restrict__ part,
                           const float* __restrict__ x, float* __restrict__ dinv,
                           half8* __restrict__ g1, int n, int e, int nbuck, int nblkE) {
    __shared__ unsigned int buf[SORT_CAP];
    __shared__ int cnt[RB];
    __shared__ int hist[NSLICE];
    int tx = threadIdx.x, b = blockIdx.x;
    cnt[tx] = 0;
    if (tx < NSLICE) hist[tx] = 0;
    __syncthreads();
    int start, end;
    bucket_range(scn, part, b, nbuck, nblkE, e, start, end);
    int len = end - start;
    bool stage = (len <= SORT_CAP);
    for (int i = tx; i < len; i += 256) {
        unsigned int p = binned[start + i];
        atomicAdd(&cnt[p >> 24], 1);
        if (stage) {
            buf[i] = p;
            atomicAdd(&hist[(p & 0xFFFFFF) >> SLICE_SHIFT], 1);
        }
    }
    __syncthreads();
    if (stage) {
        if (tx == 0) {  // tiny serial exclusive scan of 64 bins
            int s = 0;
#pragma unroll
            for (int k = 0; k < NSLICE; ++k) { int c = hist[k]; hist[k] = s; s += c; }
        }
        __syncthreads();
        for (int i = tx; i < len; i += 256) {
            unsigned int p = buf[i];
            int pos = atomicAdd(&hist[(p & 0xFFFFFF) >> SLICE_SHIFT], 1);
            binned[start + pos] = p;
        }
    }
    int node = b * RB + tx;
    if (node < n) {
        float d = rsqrtf((float)(cnt[tx] + 1));  // +1 self-loop
        dinv[node] = d;
        const float* xp = x + (size_t)node * FIN;
        half8 row = {};
#pragma unroll
        for (int f = 0; f < FIN; ++f) row[f] = (_Float16)(xp[f] * d);
        g1[node] = row;
    }
}

// layer 1: LDS-accumulate gathered fp16 g1, fused W1+relu, g2 = fp16(h*dinv)
__global__ void k_bagg1(const unsigned int* __restrict__ binned,
                        const int* __restrict__ scn, const int* __restrict__ part,
                        const half8* __restrict__ g1, const float* __restrict__ dinv,
                        const float* __restrict__ W1, const float* __restrict__ b1,
                        half8* __restrict__ g2, int n, int e, int nbuck, int nblkE) {
    __shared__ float acc[FIN * RB];  // feature-major
    int tx = threadIdx.x, b = blockIdx.x;
#pragma unroll
    for (int f = 0; f < FIN; ++f) acc[f * RB + tx] = 0.0f;
    __syncthreads();
    int start, end;
    bucket_range(scn, part, b, nbuck, nblkE, e, start, end);
    for (int i = start + tx; i < end; i += 256) {
        unsigned int p = __builtin_nontemporal_load(&binned[i]);
        int s = (int)(p & 0xFFFFFF);
        int dl = (int)(p >> 24);
        half8 hv = g1[s];                 // slice-ordered gather (hot table)
        atomicAdd(&acc[dl],          (float)hv[0]);
        atomicAdd(&acc[RB + dl],     (float)hv[1]);
        atomicAdd(&acc[2 * RB + dl], (float)hv[2]);
        atomicAdd(&acc[3 * RB + dl], (float)hv[3]);
        atomicAdd(&acc[4 * RB + dl], (float)hv[4]);
    }
    __syncthreads();
    int node = b * RB + tx;
    if (node >= n) return;
    float d = dinv[node];
    half8 gi = g1[node];
    float v[FIN];
#pragma unroll
    for (int f = 0; f < FIN; ++f) v[f] = (acc[f * RB + tx] + (float)gi[f]) * d;
    half8 go = {};
#pragma unroll
    for (int j = 0; j < FHID; ++j) {
        float s = b1[j];
#pragma unroll
        for (int k = 0; k < FIN; ++k) s = fmaf(v[k], W1[k * FHID + j], s);
        go[j] = (_Float16)(fmaxf(s, 0.0f) * d);  // relu, pre-scaled for layer 2
    }
    g2[node] = go;
}

// layer 2: LDS-accumulate gathered fp16 g2, fused W2 + log_softmax
__global__ void k_bagg2(const unsigned int* __restrict__ binned,
                        const int* __restrict__ scn, const int* __restrict__ part,
                        const half8* __restrict__ g2, const float* __restrict__ dinv,
                        const float* __restrict__ W2, const float* __restrict__ b2,
                        float* __restrict__ out, int n, int e, int nbuck, int nblkE) {
    __shared__ float acc[FHID * RB];
    int tx = threadIdx.x, b = blockIdx.x;
#pragma unroll
    for (int f = 0; f < FHID; ++f) acc[f * RB + tx] = 0.0f;
    __syncthreads();
    int start, end;
    bucket_range(scn, part, b, nbuck, nblkE, e, start, end);
    for (int i = start + tx; i < end; i += 256) {
        unsigned int p = __builtin_nontemporal_load(&binned[i]);
        int s = (int)(p & 0xFFFFFF);
        int dl = (int)(p >> 24);
        half8 hv = g2[s];
        atomicAdd(&acc[dl],          (float)hv[0]);
        atomicAdd(&acc[RB + dl],     (float)hv[1]);
        atomicAdd(&acc[2 * RB + dl], (float)hv[2]);
        atomicAdd(&acc[3 * RB + dl], (float)hv[3]);
        atomicAdd(&acc[4 * RB + dl], (float)hv[4]);
    }
    __syncthreads();
    int node = b * RB + tx;
    if (node >= n) return;
    float d = dinv[node];
    half8 gi = g2[node];
    float v[FHID];
#pragma unroll
    for (int f = 0; f < FHID; ++f) v[f] = (acc[f * RB + tx] + (float)gi[f]) * d;
    float o[FOUT];
    float m = -1e30f;
#pragma unroll
    for (int j = 0; j < FOUT; ++j) {
        float s = b2[j];
#pragma unroll
        for (int k = 0; k < FHID; ++k) s = fmaf(v[k], W2[k * FOUT + j], s);
        o[j] = s;
        m = fmaxf(m, s);
    }
    float ssum = 0.0f;
#pragma unroll
    for (int j = 0; j < FOUT; ++j) ssum += expf(o[j] - m);
    float lse = m + logf(ssum);
    float* op = out + (size_t)node * FOUT;
#pragma unroll
    for (int j = 0; j < FOUT; ++j) op[j] = o[j] - lse;
}

// ---------- fallback (R1) ----------

__global__ void f_init_deg(float* __restrict__ deg, int n) {
    int i = blockIdx.x * blockDim.x + threadIdx.x;
    if (i < n) deg[i] = 1.0f;
}
__global__ void f_count_deg(const int* __restrict__ dst, float* __restrict__ deg, int e) {
    int i = blockIdx.x * blockDim.x + threadIdx.x;
    if (i < e) atomicAdd(&deg[dst[i]], 1.0f);
}
__global__ void f_finish_deg_g1(const float* __restrict__ x, float* __restrict__ dinv,
                                float* __restrict__ g1, int n) {
    int i = blockIdx.x * blockDim.x + threadIdx.x;
    if (i >= n) return;
    float d = rsqrtf(dinv[i]);
    dinv[i] = d;
#pragma unroll
    for (int f = 0; f < FIN; ++f) g1[(size_t)i * FIN + f] = x[(size_t)i * FIN + f] * d;
}
__global__ void f_scatter5(const int* __restrict__ src, const int* __restrict__ dst,
                           const float* __restrict__ g, float* __restrict__ acc, int e) {
    int i = blockIdx.x * blockDim.x + threadIdx.x;
    if (i >= e) return;
    int s = src[i], d = dst[i];
    float* a = acc + (size_t)d * 5;
    const float* gp = g + (size_t)s * 5;
    atomicAdd(a + 0, gp[0]);
    atomicAdd(a + 1, gp[1]);
    atomicAdd(a + 2, gp[2]);
    atomicAdd(a + 3, gp[3]);
    atomicAdd(a + 4, gp[4]);
}
__global__ void f_update1(const float* __restrict__ dinv, float* __restrict__ g,
                          float* __restrict__ acc, const float* __restrict__ W1,
                          const float* __restrict__ b1, int n) {
    int i = blockIdx.x * blockDim.x + threadIdx.x;
    if (i >= n) return;
    float d = dinv[i];
    float v[FIN];
#pragma unroll
    for (int f = 0; f < FIN; ++f) {
        size_t idx = (size_t)i * FIN + f;
        v[f] = (acc[idx] + g[idx]) * d;
        acc[idx] = 0.0f;
    }
#pragma unroll
    for (int j = 0; j < FHID; ++j) {
        float s = b1[j];
#pragma unroll
        for (int k = 0; k < FIN; ++k) s += v[k] * W1[k * FHID + j];
        g[(size_t)i * FHID + j] = fmaxf(s, 0.0f) * d;
    }
}
__global__ void f_update2(const float* __restrict__ dinv, const float* __restrict__ g,
                          const float* __restrict__ acc, const float* __restrict__ W2,
                          const float* __restrict__ b2, float* __restrict__ out, int n) {
    int i = blockIdx.x * blockDim.x + threadIdx.x;
    if (i >= n) return;
    float d = dinv[i];
    float v[FHID];
#pragma unroll
    for (int f = 0; f < FHID; ++f) v[f] = (acc[(size_t)i * FHID + f] + g[(size_t)i * FHID + f]) * d;
    float o[FOUT];
    float m = -1e30f;
#pragma unroll
    for (int j = 0; j < FOUT; ++j) {
        float s = b2[j];
#pragma unroll
        for (int k = 0; k < FHID; ++k) s += v[k] * W2[k * FOUT + j];
        o[j] = s;
        m = fmaxf(m, s);
    }
    float ssum = 0.0f;
#pragma unroll
    for (int j = 0; j < FOUT; ++j) ssum += expf(o[j] - m);
    float lse = m + logf(ssum);
#pragma unroll
    for (int j = 0; j < FOUT; ++j) out[(size_t)i * FOUT + j] = o[j] - lse;
}

// ---------- launcher ----------

extern "C" void kernel_launch(void* const* d_in, const int* in_sizes, int n_in,
                              void* d_out, int out_size, void* d_ws, size_t ws_size,
                              hipStream_t stream) {
    const float* x  = (const float*)d_in[0];
    const int*   ei = (const int*)d_in[1];
    const float* W1 = (const float*)d_in[2];
    const float* b1 = (const float*)d_in[3];
    const float* W2 = (const float*)d_in[4];
    const float* b2 = (const float*)d_in[5];

    const int n = in_sizes[0] / FIN;   // 500,000
    const int e = in_sizes[1] / 2;     // 16,000,000
    const int* src = ei;
    const int* dst = ei + e;

    const int nbuck = (n + RB - 1) / RB;          // 1954
    const int nblkE = (e + EPB - 1) / EPB;        // 489
    const size_t m = (size_t)nbuck * nblkE;       // ~955k
    const int nsb = (int)((m + 255) / 256);

    size_t off = 0;
    auto alloc = [&](size_t bytes) { size_t o = off; off = (off + bytes + 15) & ~(size_t)15; return o; };
    int*          cnt    = (int*)((char*)d_ws + alloc(m * 4));
    int*          scn    = (int*)((char*)d_ws + alloc(m * 4));
    int*          part   = (int*)((char*)d_ws + alloc((size_t)nsb * 4));
    float*        dinv   = (float*)((char*)d_ws + alloc((size_t)n * 4));
    half8*        g1     = (half8*)((char*)d_ws + alloc((size_t)n * 16));
    half8*        g2     = (half8*)((char*)d_ws + alloc((size_t)n * 16));
    unsigned int* binned = (unsigned int*)((char*)d_ws + alloc((size_t)e * 4));
    const size_t need = off;

    const int B = 256;

    if (ws_size >= need && n <= (1 << 24) && nbuck <= NBUCK_MAX &&
        ((n + (1 << SLICE_SHIFT) - 1) >> SLICE_SHIFT) <= NSLICE) {
        k_binhist<<<nblkE, B, 0, stream>>>(dst, cnt, e, nbuck, nblkE);
        k_scan1<<<nsb, B, 0, stream>>>(cnt, scn, part, (int)m);
        k_scan2<<<1, B, 0, stream>>>(part, nsb);
        k_binscatter<<<nblkE, B, 0, stream>>>(src, dst, scn, part, binned, e, nbuck, nblkE);
        k_deg_sort<<<nbuck, B, 0, stream>>>(binned, scn, part, x, dinv, g1, n, e, nbuck, nblkE);
        k_bagg1<<<nbuck, B, 0, stream>>>(binned, scn, part, g1, dinv, W1, b1, g2, n, e, nbuck, nblkE);
        k_bagg2<<<nbuck, B, 0, stream>>>(binned, scn, part, g2, dinv, W2, b2, (float*)d_out, n, e, nbuck, nblkE);
    } else {
        const int gn = (n + B - 1) / B;
        const int ge = (e + B - 1) / B;
        float* fdinv = (float*)d_ws;
        float* fg    = fdinv + n;
        float* facc  = fg + (size_t)5 * n;
        hipMemsetAsync(facc, 0, (size_t)5 * n * sizeof(float), stream);
        f_init_deg<<<gn, B, 0, stream>>>(fdinv, n);
        f_count_deg<<<ge, B, 0, stream>>>(dst, fdinv, e);
        f_finish_deg_g1<<<gn, B, 0, stream>>>(x, fdinv, fg, n);
        f_scatter5<<<ge, B, 0, stream>>>(src, dst, fg, facc, e);
        f_update1<<<gn, B, 0, stream>>>(fdinv, fg, facc, W1, b1, n);
        f_scatter5<<<ge, B, 0, stream>>>(src, dst, fg, facc, e);
        f_update2<<<gn, B, 0, stream>>>(fdinv, fg, facc, W2, b2, (float*)d_out, n);
    }
}

// Round 6
// 1296.565 us; speedup vs baseline: 1.2822x; 1.0469x over previous
//
#include <hip/hip_runtime.h>
#include <math.h>

// GCN 2-layer, N=500k, E=16M, F 5->5->8.
// R6: R5 structure (bucket binning, fp16 tables, slice-sort) + latency fixes:
//   - bagg1/bagg2: 4x ILP unroll (4 gathers in flight/thread) + 512-thread
//     blocks (edge loop stride 512, epilogue tx<256)
//   - binhist/binscatter: B=1024 + 4x unroll (grid was only ~2 blocks/CU)
// All atomics in LDS. Fallback to R1 atomic-scatter if ws too small.

#define FIN 5
#define FHID 5
#define FOUT 8
#define RB 256        // nodes per bucket
#define EPB 32768     // edges per binning block
#define NBUCK_MAX 2048
#define SLICE_SHIFT 14
#define NSLICE 64
#define SORT_CAP 12288   // max staged edges per bucket (48 KB LDS)

typedef _Float16 half8 __attribute__((ext_vector_type(8)));

// ---------- binning ----------

__global__ void k_binhist(const int* __restrict__ dst, int* __restrict__ cnt,
                          int e, int nbuck, int nblkE) {
    __shared__ int hist[NBUCK_MAX];
    int tx = threadIdx.x, blk = blockIdx.x;
    for (int b = tx; b < nbuck; b += 1024) hist[b] = 0;
    __syncthreads();
    size_t base = (size_t)blk * EPB;
    for (int k = 0; k < EPB; k += 4096) {
        size_t i0 = base + k + tx;
        int d0 = (i0 < (size_t)e) ? __builtin_nontemporal_load(&dst[i0]) : -1;
        int d1 = (i0 + 1024 < (size_t)e) ? __builtin_nontemporal_load(&dst[i0 + 1024]) : -1;
        int d2 = (i0 + 2048 < (size_t)e) ? __builtin_nontemporal_load(&dst[i0 + 2048]) : -1;
        int d3 = (i0 + 3072 < (size_t)e) ? __builtin_nontemporal_load(&dst[i0 + 3072]) : -1;
        if (d0 >= 0) atomicAdd(&hist[d0 >> 8], 1);
        if (d1 >= 0) atomicAdd(&hist[d1 >> 8], 1);
        if (d2 >= 0) atomicAdd(&hist[d2 >> 8], 1);
        if (d3 >= 0) atomicAdd(&hist[d3 >> 8], 1);
    }
    __syncthreads();
    for (int b = tx; b < nbuck; b += 1024) cnt[(size_t)b * nblkE + blk] = hist[b];
}

__global__ void k_scan1(const int* __restrict__ t, int* __restrict__ scn,
                        int* __restrict__ partial, int n) {
    __shared__ int sh[256];
    int tx = threadIdx.x;
    int i = blockIdx.x * 256 + tx;
    int v = (i < n) ? t[i] : 0;
    sh[tx] = v;
    __syncthreads();
    for (int off = 1; off < 256; off <<= 1) {
        int add = (tx >= off) ? sh[tx - off] : 0;
        __syncthreads();
        sh[tx] += add;
        __syncthreads();
    }
    if (i < n) scn[i] = sh[tx] - v;
    if (tx == 255) partial[blockIdx.x] = sh[255];
}

__global__ void k_scan2(int* __restrict__ partial, int nb) {
    __shared__ int sh[256];
    __shared__ int carry;
    int tx = threadIdx.x;
    if (tx == 0) carry = 0;
    __syncthreads();
    for (int base = 0; base < nb; base += 256) {
        int i = base + tx;
        int v = (i < nb) ? partial[i] : 0;
        int c0 = carry;
        sh[tx] = v;
        __syncthreads();
        for (int off = 1; off < 256; off <<= 1) {
            int add = (tx >= off) ? sh[tx - off] : 0;
            __syncthreads();
            sh[tx] += add;
            __syncthreads();
        }
        if (i < nb) partial[i] = c0 + sh[tx] - v;
        __syncthreads();
        if (tx == 0) carry = c0 + sh[255];
        __syncthreads();
    }
}

__global__ void k_binscatter(const int* __restrict__ src, const int* __restrict__ dst,
                             const int* __restrict__ scn, const int* __restrict__ part,
                             unsigned int* __restrict__ binned,
                             int e, int nbuck, int nblkE) {
    __shared__ int cur[NBUCK_MAX];
    int tx = threadIdx.x, blk = blockIdx.x;
    for (int b = tx; b < nbuck; b += 1024) {
        size_t idx = (size_t)b * nblkE + blk;
        cur[b] = scn[idx] + part[idx >> 8];
    }
    __syncthreads();
    size_t base = (size_t)blk * EPB;
    for (int k = 0; k < EPB; k += 4096) {
        size_t i0 = base + k + tx;
        int d0 = (i0 < (size_t)e) ? __builtin_nontemporal_load(&dst[i0]) : -1;
        int d1 = (i0 + 1024 < (size_t)e) ? __builtin_nontemporal_load(&dst[i0 + 1024]) : -1;
        int d2 = (i0 + 2048 < (size_t)e) ? __builtin_nontemporal_load(&dst[i0 + 2048]) : -1;
        int d3 = (i0 + 3072 < (size_t)e) ? __builtin_nontemporal_load(&dst[i0 + 3072]) : -1;
        int s0 = (d0 >= 0) ? __builtin_nontemporal_load(&src[i0]) : 0;
        int s1 = (d1 >= 0) ? __builtin_nontemporal_load(&src[i0 + 1024]) : 0;
        int s2 = (d2 >= 0) ? __builtin_nontemporal_load(&src[i0 + 2048]) : 0;
        int s3 = (d3 >= 0) ? __builtin_nontemporal_load(&src[i0 + 3072]) : 0;
        if (d0 >= 0) { int p = atomicAdd(&cur[d0 >> 8], 1);
            binned[p] = ((unsigned int)(d0 & (RB - 1)) << 24) | (unsigned int)s0; }
        if (d1 >= 0) { int p = atomicAdd(&cur[d1 >> 8], 1);
            binned[p] = ((unsigned int)(d1 & (RB - 1)) << 24) | (unsigned int)s1; }
        if (d2 >= 0) { int p = atomicAdd(&cur[d2 >> 8], 1);
            binned[p] = ((unsigned int)(d2 & (RB - 1)) << 24) | (unsigned int)s2; }
        if (d3 >= 0) { int p = atomicAdd(&cur[d3 >> 8], 1);
            binned[p] = ((unsigned int)(d3 & (RB - 1)) << 24) | (unsigned int)s3; }
    }
}

// ---------- per-bucket passes ----------

__device__ __forceinline__ void bucket_range(const int* __restrict__ scn,
                                             const int* __restrict__ part,
                                             int b, int nbuck, int nblkE, int e,
                                             int& start, int& end) {
    size_t i0 = (size_t)b * nblkE;
    start = scn[i0] + part[i0 >> 8];
    if (b + 1 < nbuck) {
        size_t i1 = (size_t)(b + 1) * nblkE;
        end = scn[i1] + part[i1 >> 8];
    } else {
        end = e;
    }
}

// degree -> dinv, g1 = fp16(x*dinv), AND in-place slice-sort of the bucket's
// edge segment by src>>SLICE_SHIFT (skipped for oversized buckets).
__global__ void k_deg_sort(unsigned int* __restrict__ binned,
                           const int* __restrict__ scn, const int* __restrict__ part,
                           const float* __restrict__ x, float* __restrict__ dinv,
                           half8* __restrict__ g1, int n, int e, int nbuck, int nblkE) {
    __shared__ unsigned int buf[SORT_CAP];
    __shared__ int cnt[RB];
    __shared__ int hist[NSLICE];
    int tx = threadIdx.x, b = blockIdx.x;
    cnt[tx] = 0;
    if (tx < NSLICE) hist[tx] = 0;
    __syncthreads();
    int start, end;
    bucket_range(scn, part, b, nbuck, nblkE, e, start, end);
    int len = end - start;
    bool stage = (len <= SORT_CAP);
    for (int i = tx; i < len; i += 256) {
        unsigned int p = binned[start + i];
        atomicAdd(&cnt[p >> 24], 1);
        if (stage) {
            buf[i] = p;
            atomicAdd(&hist[(p & 0xFFFFFF) >> SLICE_SHIFT], 1);
        }
    }
    __syncthreads();
    if (stage) {
        if (tx == 0) {
            int s = 0;
#pragma unroll
            for (int k = 0; k < NSLICE; ++k) { int c = hist[k]; hist[k] = s; s += c; }
        }
        __syncthreads();
        for (int i = tx; i < len; i += 256) {
            unsigned int p = buf[i];
            int pos = atomicAdd(&hist[(p & 0xFFFFFF) >> SLICE_SHIFT], 1);
            binned[start + pos] = p;
        }
    }
    int node = b * RB + tx;
    if (node < n) {
        float d = rsqrtf((float)(cnt[tx] + 1));  // +1 self-loop
        dinv[node] = d;
        const float* xp = x + (size_t)node * FIN;
        half8 row = {};
#pragma unroll
        for (int f = 0; f < FIN; ++f) row[f] = (_Float16)(xp[f] * d);
        g1[node] = row;
    }
}

__device__ __forceinline__ void acc5(float* acc, unsigned int p, half8 hv) {
    int dl = (int)(p >> 24);
    atomicAdd(&acc[dl],          (float)hv[0]);
    atomicAdd(&acc[RB + dl],     (float)hv[1]);
    atomicAdd(&acc[2 * RB + dl], (float)hv[2]);
    atomicAdd(&acc[3 * RB + dl], (float)hv[3]);
    atomicAdd(&acc[4 * RB + dl], (float)hv[4]);
}

// layer 1: 512 threads, 4x-unrolled gathers, LDS f32 accumulate,
// fused W1+relu epilogue (tx<256), g2 = fp16(h*dinv)
__global__ void k_bagg1(const unsigned int* __restrict__ binned,
                        const int* __restrict__ scn, const int* __restrict__ part,
                        const half8* __restrict__ g1, const float* __restrict__ dinv,
                        const float* __restrict__ W1, const float* __restrict__ b1,
                        half8* __restrict__ g2, int n, int e, int nbuck, int nblkE) {
    __shared__ float acc[FIN * RB];
    int tx = threadIdx.x, b = blockIdx.x;
    for (int f = tx; f < FIN * RB; f += 512) acc[f] = 0.0f;
    __syncthreads();
    int start, end;
    bucket_range(scn, part, b, nbuck, nblkE, e, start, end);
    int i = start + tx;
    for (; i + 1536 < end; i += 2048) {
        unsigned int p0 = __builtin_nontemporal_load(&binned[i]);
        unsigned int p1 = __builtin_nontemporal_load(&binned[i + 512]);
        unsigned int p2 = __builtin_nontemporal_load(&binned[i + 1024]);
        unsigned int p3 = __builtin_nontemporal_load(&binned[i + 1536]);
        half8 v0 = g1[p0 & 0xFFFFFF];
        half8 v1 = g1[p1 & 0xFFFFFF];
        half8 v2 = g1[p2 & 0xFFFFFF];
        half8 v3 = g1[p3 & 0xFFFFFF];
        acc5(acc, p0, v0);
        acc5(acc, p1, v1);
        acc5(acc, p2, v2);
        acc5(acc, p3, v3);
    }
    for (; i < end; i += 512) {
        unsigned int p = __builtin_nontemporal_load(&binned[i]);
        half8 v = g1[p & 0xFFFFFF];
        acc5(acc, p, v);
    }
    __syncthreads();
    if (tx >= RB) return;
    int node = b * RB + tx;
    if (node >= n) return;
    float d = dinv[node];
    half8 gi = g1[node];
    float v[FIN];
#pragma unroll
    for (int f = 0; f < FIN; ++f) v[f] = (acc[f * RB + tx] + (float)gi[f]) * d;
    half8 go = {};
#pragma unroll
    for (int j = 0; j < FHID; ++j) {
        float s = b1[j];
#pragma unroll
        for (int k = 0; k < FIN; ++k) s = fmaf(v[k], W1[k * FHID + j], s);
        go[j] = (_Float16)(fmaxf(s, 0.0f) * d);  // relu, pre-scaled for layer 2
    }
    g2[node] = go;
}

// layer 2: same structure, fused W2 + log_softmax epilogue
__global__ void k_bagg2(const unsigned int* __restrict__ binned,
                        const int* __restrict__ scn, const int* __restrict__ part,
                        const half8* __restrict__ g2, const float* __restrict__ dinv,
                        const float* __restrict__ W2, const float* __restrict__ b2,
                        float* __restrict__ out, int n, int e, int nbuck, int nblkE) {
    __shared__ float acc[FHID * RB];
    int tx = threadIdx.x, b = blockIdx.x;
    for (int f = tx; f < FHID * RB; f += 512) acc[f] = 0.0f;
    __syncthreads();
    int start, end;
    bucket_range(scn, part, b, nbuck, nblkE, e, start, end);
    int i = start + tx;
    for (; i + 1536 < end; i += 2048) {
        unsigned int p0 = __builtin_nontemporal_load(&binned[i]);
        unsigned int p1 = __builtin_nontemporal_load(&binned[i + 512]);
        unsigned int p2 = __builtin_nontemporal_load(&binned[i + 1024]);
        unsigned int p3 = __builtin_nontemporal_load(&binned[i + 1536]);
        half8 v0 = g2[p0 & 0xFFFFFF];
        half8 v1 = g2[p1 & 0xFFFFFF];
        half8 v2 = g2[p2 & 0xFFFFFF];
        half8 v3 = g2[p3 & 0xFFFFFF];
        acc5(acc, p0, v0);
        acc5(acc, p1, v1);
        acc5(acc, p2, v2);
        acc5(acc, p3, v3);
    }
    for (; i < end; i += 512) {
        unsigned int p = __builtin_nontemporal_load(&binned[i]);
        half8 v = g2[p & 0xFFFFFF];
        acc5(acc, p, v);
    }
    __syncthreads();
    if (tx >= RB) return;
    int node = b * RB + tx;
    if (node >= n) return;
    float d = dinv[node];
    half8 gi = g2[node];
    float v[FHID];
#pragma unroll
    for (int f = 0; f < FHID; ++f) v[f] = (acc[f * RB + tx] + (float)gi[f]) * d;
    float o[FOUT];
    float m = -1e30f;
#pragma unroll
    for (int j = 0; j < FOUT; ++j) {
        float s = b2[j];
#pragma unroll
        for (int k = 0; k < FHID; ++k) s = fmaf(v[k], W2[k * FOUT + j], s);
        o[j] = s;
        m = fmaxf(m, s);
    }
    float ssum = 0.0f;
#pragma unroll
    for (int j = 0; j < FOUT; ++j) ssum += expf(o[j] - m);
    float lse = m + logf(ssum);
    float* op = out + (size_t)node * FOUT;
#pragma unroll
    for (int j = 0; j < FOUT; ++j) op[j] = o[j] - lse;
}

// ---------- fallback (R1) ----------

__global__ void f_init_deg(float* __restrict__ deg, int n) {
    int i = blockIdx.x * blockDim.x + threadIdx.x;
    if (i < n) deg[i] = 1.0f;
}
__global__ void f_count_deg(const int* __restrict__ dst, float* __restrict__ deg, int e) {
    int i = blockIdx.x * blockDim.x + threadIdx.x;
    if (i < e) atomicAdd(&deg[dst[i]], 1.0f);
}
__global__ void f_finish_deg_g1(const float* __restrict__ x, float* __restrict__ dinv,
                                float* __restrict__ g1, int n) {
    int i = blockIdx.x * blockDim.x + threadIdx.x;
    if (i >= n) return;
    float d = rsqrtf(dinv[i]);
    dinv[i] = d;
#pragma unroll
    for (int f = 0; f < FIN; ++f) g1[(size_t)i * FIN + f] = x[(size_t)i * FIN + f] * d;
}
__global__ void f_scatter5(const int* __restrict__ src, const int* __restrict__ dst,
                           const float* __restrict__ g, float* __restrict__ acc, int e) {
    int i = blockIdx.x * blockDim.x + threadIdx.x;
    if (i >= e) return;
    int s = src[i], d = dst[i];
    float* a = acc + (size_t)d * 5;
    const float* gp = g + (size_t)s * 5;
    atomicAdd(a + 0, gp[0]);
    atomicAdd(a + 1, gp[1]);
    atomicAdd(a + 2, gp[2]);
    atomicAdd(a + 3, gp[3]);
    atomicAdd(a + 4, gp[4]);
}
__global__ void f_update1(const float* __restrict__ dinv, float* __restrict__ g,
                          float* __restrict__ acc, const float* __restrict__ W1,
                          const float* __restrict__ b1, int n) {
    int i = blockIdx.x * blockDim.x + threadIdx.x;
    if (i >= n) return;
    float d = dinv[i];
    float v[FIN];
#pragma unroll
    for (int f = 0; f < FIN; ++f) {
        size_t idx = (size_t)i * FIN + f;
        v[f] = (acc[idx] + g[idx]) * d;
        acc[idx] = 0.0f;
    }
#pragma unroll
    for (int j = 0; j < FHID; ++j) {
        float s = b1[j];
#pragma unroll
        for (int k = 0; k < FIN; ++k) s += v[k] * W1[k * FHID + j];
        g[(size_t)i * FHID + j] = fmaxf(s, 0.0f) * d;
    }
}
__global__ void f_update2(const float* __restrict__ dinv, const float* __restrict__ g,
                          const float* __restrict__ acc, const float* __restrict__ W2,
                          const float* __restrict__ b2, float* __restrict__ out, int n) {
    int i = blockIdx.x * blockDim.x + threadIdx.x;
    if (i >= n) return;
    float d = dinv[i];
    float v[FHID];
#pragma unroll
    for (int f = 0; f < FHID; ++f) v[f] = (acc[(size_t)i * FHID + f] + g[(size_t)i * FHID + f]) * d;
    float o[FOUT];
    float m = -1e30f;
#pragma unroll
    for (int j = 0; j < FOUT; ++j) {
        float s = b2[j];
#pragma unroll
        for (int k = 0; k < FHID; ++k) s += v[k] * W2[k * FOUT + j];
        o[j] = s;
        m = fmaxf(m, s);
    }
    float ssum = 0.0f;
#pragma unroll
    for (int j = 0; j < FOUT; ++j) ssum += expf(o[j] - m);
    float lse = m + logf(ssum);
#pragma unroll
    for (int j = 0; j < FOUT; ++j) out[(size_t)i * FOUT + j] = o[j] - lse;
}

// ---------- launcher ----------

extern "C" void kernel_launch(void* const* d_in, const int* in_sizes, int n_in,
                              void* d_out, int out_size, void* d_ws, size_t ws_size,
                              hipStream_t stream) {
    const float* x  = (const float*)d_in[0];
    const int*   ei = (const int*)d_in[1];
    const float* W1 = (const float*)d_in[2];
    const float* b1 = (const float*)d_in[3];
    const float* W2 = (const float*)d_in[4];
    const float* b2 = (const float*)d_in[5];

    const int n = in_sizes[0] / FIN;   // 500,000
    const int e = in_sizes[1] / 2;     // 16,000,000
    const int* src = ei;
    const int* dst = ei + e;

    const int nbuck = (n + RB - 1) / RB;          // 1954
    const int nblkE = (e + EPB - 1) / EPB;        // 489
    const size_t m = (size_t)nbuck * nblkE;       // ~955k
    const int nsb = (int)((m + 255) / 256);

    size_t off = 0;
    auto alloc = [&](size_t bytes) { size_t o = off; off = (off + bytes + 15) & ~(size_t)15; return o; };
    int*          cnt    = (int*)((char*)d_ws + alloc(m * 4));
    int*          scn    = (int*)((char*)d_ws + alloc(m * 4));
    int*          part   = (int*)((char*)d_ws + alloc((size_t)nsb * 4));
    float*        dinv   = (float*)((char*)d_ws + alloc((size_t)n * 4));
    half8*        g1     = (half8*)((char*)d_ws + alloc((size_t)n * 16));
    half8*        g2     = (half8*)((char*)d_ws + alloc((size_t)n * 16));
    unsigned int* binned = (unsigned int*)((char*)d_ws + alloc((size_t)e * 4));
    const size_t need = off;

    if (ws_size >= need && n <= (1 << 24) && nbuck <= NBUCK_MAX &&
        ((n + (1 << SLICE_SHIFT) - 1) >> SLICE_SHIFT) <= NSLICE) {
        k_binhist<<<nblkE, 1024, 0, stream>>>(dst, cnt, e, nbuck, nblkE);
        k_scan1<<<nsb, 256, 0, stream>>>(cnt, scn, part, (int)m);
        k_scan2<<<1, 256, 0, stream>>>(part, nsb);
        k_binscatter<<<nblkE, 1024, 0, stream>>>(src, dst, scn, part, binned, e, nbuck, nblkE);
        k_deg_sort<<<nbuck, 256, 0, stream>>>(binned, scn, part, x, dinv, g1, n, e, nbuck, nblkE);
        k_bagg1<<<nbuck, 512, 0, stream>>>(binned, scn, part, g1, dinv, W1, b1, g2, n, e, nbuck, nblkE);
        k_bagg2<<<nbuck, 512, 0, stream>>>(binned, scn, part, g2, dinv, W2, b2, (float*)d_out, n, e, nbuck, nblkE);
    } else {
        const int B = 256;
        const int gn = (n + B - 1) / B;
        const int ge = (e + B - 1) / B;
        float* fdinv = (float*)d_ws;
        float* fg    = fdinv + n;
        float* facc  = fg + (size_t)5 * n;
        hipMemsetAsync(facc, 0, (size_t)5 * n * sizeof(float), stream);
        f_init_deg<<<gn, B, 0, stream>>>(fdinv, n);
        f_count_deg<<<ge, B, 0, stream>>>(dst, fdinv, e);
        f_finish_deg_g1<<<gn, B, 0, stream>>>(x, fdinv, fg, n);
        f_scatter5<<<ge, B, 0, stream>>>(src, dst, fg, facc, e);
        f_update1<<<gn, B, 0, stream>>>(fdinv, fg, facc, W1, b1, n);
        f_scatter5<<<ge, B, 0, stream>>>(src, dst, fg, facc, e);
        f_update2<<<gn, B, 0, stream>>>(fdinv, fg, facc, W2, b2, (float*)d_out, n);
    }
}

// Round 7
// 806.437 us; speedup vs baseline: 2.0615x; 1.6078x over previous
//
#include <hip/hip_runtime.h>
#include <math.h>

// GCN 2-layer, N=500k, E=16M, F 5->5->8.
// R7: aggregation WITHOUT LDS atomics (R3-R6 invariant ~430us/pass traced to
//     the 5 divergent LDS atomics per edge; R2's shfl version was ~5x faster).
//   - binhist/scan/binscatter: unchanged (dst-bucket binning, packed u32)
//   - k_deg_dsort: per-bucket dst-sort (by dl) in LDS + per-node CSR offsets
//     (nodeptr) + degree/dinv/g1 in one pass
//   - k_agg1/2: 16 lanes per node, register accumulate, __shfl_xor reduce,
//     fused dense epilogues. Zero atomics of any kind.
// Fallback to R1 atomic-scatter if ws too small.

#define FIN 5
#define FHID 5
#define FOUT 8
#define RB 256        // nodes per bucket
#define EPB 32768     // edges per binning block
#define NBUCK_MAX 2048
#define SORT_CAP 12288   // max staged edges per bucket (48 KB LDS)

typedef _Float16 half8 __attribute__((ext_vector_type(8)));

// ---------- binning ----------

__global__ void k_binhist(const int* __restrict__ dst, int* __restrict__ cnt,
                          int e, int nbuck, int nblkE) {
    __shared__ int hist[NBUCK_MAX];
    int tx = threadIdx.x, blk = blockIdx.x;
    for (int b = tx; b < nbuck; b += 1024) hist[b] = 0;
    __syncthreads();
    size_t base = (size_t)blk * EPB;
    for (int k = 0; k < EPB; k += 4096) {
        size_t i0 = base + k + tx;
        int d0 = (i0 < (size_t)e) ? __builtin_nontemporal_load(&dst[i0]) : -1;
        int d1 = (i0 + 1024 < (size_t)e) ? __builtin_nontemporal_load(&dst[i0 + 1024]) : -1;
        int d2 = (i0 + 2048 < (size_t)e) ? __builtin_nontemporal_load(&dst[i0 + 2048]) : -1;
        int d3 = (i0 + 3072 < (size_t)e) ? __builtin_nontemporal_load(&dst[i0 + 3072]) : -1;
        if (d0 >= 0) atomicAdd(&hist[d0 >> 8], 1);
        if (d1 >= 0) atomicAdd(&hist[d1 >> 8], 1);
        if (d2 >= 0) atomicAdd(&hist[d2 >> 8], 1);
        if (d3 >= 0) atomicAdd(&hist[d3 >> 8], 1);
    }
    __syncthreads();
    for (int b = tx; b < nbuck; b += 1024) cnt[(size_t)b * nblkE + blk] = hist[b];
}

__global__ void k_scan1(const int* __restrict__ t, int* __restrict__ scn,
                        int* __restrict__ partial, int n) {
    __shared__ int sh[256];
    int tx = threadIdx.x;
    int i = blockIdx.x * 256 + tx;
    int v = (i < n) ? t[i] : 0;
    sh[tx] = v;
    __syncthreads();
    for (int off = 1; off < 256; off <<= 1) {
        int add = (tx >= off) ? sh[tx - off] : 0;
        __syncthreads();
        sh[tx] += add;
        __syncthreads();
    }
    if (i < n) scn[i] = sh[tx] - v;
    if (tx == 255) partial[blockIdx.x] = sh[255];
}

__global__ void k_scan2(int* __restrict__ partial, int nb) {
    __shared__ int sh[256];
    __shared__ int carry;
    int tx = threadIdx.x;
    if (tx == 0) carry = 0;
    __syncthreads();
    for (int base = 0; base < nb; base += 256) {
        int i = base + tx;
        int v = (i < nb) ? partial[i] : 0;
        int c0 = carry;
        sh[tx] = v;
        __syncthreads();
        for (int off = 1; off < 256; off <<= 1) {
            int add = (tx >= off) ? sh[tx - off] : 0;
            __syncthreads();
            sh[tx] += add;
            __syncthreads();
        }
        if (i < nb) partial[i] = c0 + sh[tx] - v;
        __syncthreads();
        if (tx == 0) carry = c0 + sh[255];
        __syncthreads();
    }
}

__global__ void k_binscatter(const int* __restrict__ src, const int* __restrict__ dst,
                             const int* __restrict__ scn, const int* __restrict__ part,
                             unsigned int* __restrict__ binned,
                             int e, int nbuck, int nblkE) {
    __shared__ int cur[NBUCK_MAX];
    int tx = threadIdx.x, blk = blockIdx.x;
    for (int b = tx; b < nbuck; b += 1024) {
        size_t idx = (size_t)b * nblkE + blk;
        cur[b] = scn[idx] + part[idx >> 8];
    }
    __syncthreads();
    size_t base = (size_t)blk * EPB;
    for (int k = 0; k < EPB; k += 4096) {
        size_t i0 = base + k + tx;
        int d0 = (i0 < (size_t)e) ? __builtin_nontemporal_load(&dst[i0]) : -1;
        int d1 = (i0 + 1024 < (size_t)e) ? __builtin_nontemporal_load(&dst[i0 + 1024]) : -1;
        int d2 = (i0 + 2048 < (size_t)e) ? __builtin_nontemporal_load(&dst[i0 + 2048]) : -1;
        int d3 = (i0 + 3072 < (size_t)e) ? __builtin_nontemporal_load(&dst[i0 + 3072]) : -1;
        int s0 = (d0 >= 0) ? __builtin_nontemporal_load(&src[i0]) : 0;
        int s1 = (d1 >= 0) ? __builtin_nontemporal_load(&src[i0 + 1024]) : 0;
        int s2 = (d2 >= 0) ? __builtin_nontemporal_load(&src[i0 + 2048]) : 0;
        int s3 = (d3 >= 0) ? __builtin_nontemporal_load(&src[i0 + 3072]) : 0;
        if (d0 >= 0) { int p = atomicAdd(&cur[d0 >> 8], 1);
            binned[p] = ((unsigned int)(d0 & (RB - 1)) << 24) | (unsigned int)s0; }
        if (d1 >= 0) { int p = atomicAdd(&cur[d1 >> 8], 1);
            binned[p] = ((unsigned int)(d1 & (RB - 1)) << 24) | (unsigned int)s1; }
        if (d2 >= 0) { int p = atomicAdd(&cur[d2 >> 8], 1);
            binned[p] = ((unsigned int)(d2 & (RB - 1)) << 24) | (unsigned int)s2; }
        if (d3 >= 0) { int p = atomicAdd(&cur[d3 >> 8], 1);
            binned[p] = ((unsigned int)(d3 & (RB - 1)) << 24) | (unsigned int)s3; }
    }
}

// ---------- per-bucket dst-sort + degree + g1 ----------

__device__ __forceinline__ void bucket_range(const int* __restrict__ scn,
                                             const int* __restrict__ part,
                                             int b, int nbuck, int nblkE, int e,
                                             int& start, int& end) {
    size_t i0 = (size_t)b * nblkE;
    start = scn[i0] + part[i0 >> 8];
    if (b + 1 < nbuck) {
        size_t i1 = (size_t)(b + 1) * nblkE;
        end = scn[i1] + part[i1 >> 8];
    } else {
        end = e;
    }
}

// dst-sort the bucket's edge segment in place (counting sort by dl), emit
// per-node absolute CSR starts (nodeptr), degree -> dinv, g1 = fp16(x*dinv).
// Oversized buckets (len > SORT_CAP): leave unsorted, nodeptr = -1 sentinel.
__global__ void k_deg_dsort(unsigned int* __restrict__ binned,
                            const int* __restrict__ scn, const int* __restrict__ part,
                            const float* __restrict__ x, float* __restrict__ dinv,
                            half8* __restrict__ g1, int* __restrict__ nodeptr,
                            int n, int e, int nbuck, int nblkE) {
    __shared__ unsigned int buf[SORT_CAP];
    __shared__ int cnt[RB];
    __shared__ int sh[RB];
    __shared__ int base[RB];
    int tx = threadIdx.x, b = blockIdx.x;
    cnt[tx] = 0;
    __syncthreads();
    int start, end;
    bucket_range(scn, part, b, nbuck, nblkE, e, start, end);
    int len = end - start;
    bool stage = (len <= SORT_CAP);
    for (int i = tx; i < len; i += 256) {
        unsigned int p = binned[start + i];
        atomicAdd(&cnt[p >> 24], 1);
        if (stage) buf[i] = p;
    }
    __syncthreads();
    // block-wide inclusive scan of cnt -> exclusive in excl
    int v = cnt[tx];
    sh[tx] = v;
    __syncthreads();
    for (int off = 1; off < 256; off <<= 1) {
        int add = (tx >= off) ? sh[tx - off] : 0;
        __syncthreads();
        sh[tx] += add;
        __syncthreads();
    }
    int excl = sh[tx] - v;
    nodeptr[(size_t)b * RB + tx] = stage ? (start + excl) : -1;
    base[tx] = excl;
    __syncthreads();
    if (stage) {
        for (int i = tx; i < len; i += 256) {
            unsigned int p = buf[i];
            int pos = atomicAdd(&base[p >> 24], 1);
            binned[start + pos] = p;
        }
    }
    int node = b * RB + tx;
    if (node < n) {
        float d = rsqrtf((float)(cnt[tx] + 1));  // +1 self-loop
        dinv[node] = d;
        const float* xp = x + (size_t)node * FIN;
        half8 row = {};
#pragma unroll
        for (int f = 0; f < FIN; ++f) row[f] = (_Float16)(xp[f] * d);
        g1[node] = row;
    }
}

// ---------- atomic-free aggregation: 16 lanes per node, shfl reduce ----------

// layer 1: v = (sum_{src} g1[src] + g1[node]) * dinv ; g2 = fp16(relu(v@W1+b1)*dinv)
__global__ void k_agg1(const unsigned int* __restrict__ binned,
                       const int* __restrict__ nodeptr,
                       const int* __restrict__ scn, const int* __restrict__ part,
                       const half8* __restrict__ g1, const float* __restrict__ dinv,
                       const float* __restrict__ W1, const float* __restrict__ b1,
                       half8* __restrict__ g2, int n, int e, int nbuck, int nblkE) {
    int tid = blockIdx.x * blockDim.x + threadIdx.x;
    int node = tid >> 4;
    int lane = tid & 15;
    if (node >= n) return;
    int o0 = nodeptr[node];
    float a0 = 0, a1 = 0, a2 = 0, a3 = 0, a4 = 0;
    if (o0 >= 0) {
        int b = node >> 8;
        int dl = node & (RB - 1);
        int o1;
        if (dl == RB - 1) {
            int s_, e_;
            bucket_range(scn, part, b, nbuck, nblkE, e, s_, e_);
            o1 = e_;
        } else {
            o1 = nodeptr[node + 1];
        }
        for (int k = o0 + lane; k < o1; k += 16) {
            unsigned int p = __builtin_nontemporal_load(&binned[k]);
            half8 hv = g1[p & 0xFFFFFF];
            a0 += (float)hv[0]; a1 += (float)hv[1]; a2 += (float)hv[2];
            a3 += (float)hv[3]; a4 += (float)hv[4];
        }
    } else {
        // oversized bucket fallback: scan whole segment, filter by dl
        int b = node >> 8;
        int dl = node & (RB - 1);
        int s_, e_;
        bucket_range(scn, part, b, nbuck, nblkE, e, s_, e_);
        for (int k = s_ + lane; k < e_; k += 16) {
            unsigned int p = binned[k];
            if ((int)(p >> 24) == dl) {
                half8 hv = g1[p & 0xFFFFFF];
                a0 += (float)hv[0]; a1 += (float)hv[1]; a2 += (float)hv[2];
                a3 += (float)hv[3]; a4 += (float)hv[4];
            }
        }
    }
#pragma unroll
    for (int off = 1; off < 16; off <<= 1) {
        a0 += __shfl_xor(a0, off, 16);
        a1 += __shfl_xor(a1, off, 16);
        a2 += __shfl_xor(a2, off, 16);
        a3 += __shfl_xor(a3, off, 16);
        a4 += __shfl_xor(a4, off, 16);
    }
    if (lane == 0) {
        float d = dinv[node];
        half8 gi = g1[node];
        float v[FIN];
        v[0] = (a0 + (float)gi[0]) * d;
        v[1] = (a1 + (float)gi[1]) * d;
        v[2] = (a2 + (float)gi[2]) * d;
        v[3] = (a3 + (float)gi[3]) * d;
        v[4] = (a4 + (float)gi[4]) * d;
        half8 go = {};
#pragma unroll
        for (int j = 0; j < FHID; ++j) {
            float s = b1[j];
#pragma unroll
            for (int k = 0; k < FIN; ++k) s = fmaf(v[k], W1[k * FHID + j], s);
            go[j] = (_Float16)(fmaxf(s, 0.0f) * d);  // relu, pre-scaled for layer 2
        }
        g2[node] = go;
    }
}

// layer 2: same gather/reduce, fused W2 + log_softmax epilogue
__global__ void k_agg2(const unsigned int* __restrict__ binned,
                       const int* __restrict__ nodeptr,
                       const int* __restrict__ scn, const int* __restrict__ part,
                       const half8* __restrict__ g2, const float* __restrict__ dinv,
                       const float* __restrict__ W2, const float* __restrict__ b2,
                       float* __restrict__ out, int n, int e, int nbuck, int nblkE) {
    int tid = blockIdx.x * blockDim.x + threadIdx.x;
    int node = tid >> 4;
    int lane = tid & 15;
    if (node >= n) return;
    int o0 = nodeptr[node];
    float a0 = 0, a1 = 0, a2 = 0, a3 = 0, a4 = 0;
    if (o0 >= 0) {
        int b = node >> 8;
        int dl = node & (RB - 1);
        int o1;
        if (dl == RB - 1) {
            int s_, e_;
            bucket_range(scn, part, b, nbuck, nblkE, e, s_, e_);
            o1 = e_;
        } else {
            o1 = nodeptr[node + 1];
        }
        for (int k = o0 + lane; k < o1; k += 16) {
            unsigned int p = __builtin_nontemporal_load(&binned[k]);
            half8 hv = g2[p & 0xFFFFFF];
            a0 += (float)hv[0]; a1 += (float)hv[1]; a2 += (float)hv[2];
            a3 += (float)hv[3]; a4 += (float)hv[4];
        }
    } else {
        int b = node >> 8;
        int dl = node & (RB - 1);
        int s_, e_;
        bucket_range(scn, part, b, nbuck, nblkE, e, s_, e_);
        for (int k = s_ + lane; k < e_; k += 16) {
            unsigned int p = binned[k];
            if ((int)(p >> 24) == dl) {
                half8 hv = g2[p & 0xFFFFFF];
                a0 += (float)hv[0]; a1 += (float)hv[1]; a2 += (float)hv[2];
                a3 += (float)hv[3]; a4 += (float)hv[4];
            }
        }
    }
#pragma unroll
    for (int off = 1; off < 16; off <<= 1) {
        a0 += __shfl_xor(a0, off, 16);
        a1 += __shfl_xor(a1, off, 16);
        a2 += __shfl_xor(a2, off, 16);
        a3 += __shfl_xor(a3, off, 16);
        a4 += __shfl_xor(a4, off, 16);
    }
    if (lane == 0) {
        float d = dinv[node];
        half8 gi = g2[node];
        float v[FHID];
        v[0] = (a0 + (float)gi[0]) * d;
        v[1] = (a1 + (float)gi[1]) * d;
        v[2] = (a2 + (float)gi[2]) * d;
        v[3] = (a3 + (float)gi[3]) * d;
        v[4] = (a4 + (float)gi[4]) * d;
        float o[FOUT];
        float m = -1e30f;
#pragma unroll
        for (int j = 0; j < FOUT; ++j) {
            float s = b2[j];
#pragma unroll
            for (int k = 0; k < FHID; ++k) s = fmaf(v[k], W2[k * FOUT + j], s);
            o[j] = s;
            m = fmaxf(m, s);
        }
        float ssum = 0.0f;
#pragma unroll
        for (int j = 0; j < FOUT; ++j) ssum += expf(o[j] - m);
        float lse = m + logf(ssum);
        float* op = out + (size_t)node * FOUT;
#pragma unroll
        for (int j = 0; j < FOUT; ++j) op[j] = o[j] - lse;
    }
}

// ---------- fallback (R1) ----------

__global__ void f_init_deg(float* __restrict__ deg, int n) {
    int i = blockIdx.x * blockDim.x + threadIdx.x;
    if (i < n) deg[i] = 1.0f;
}
__global__ void f_count_deg(const int* __restrict__ dst, float* __restrict__ deg, int e) {
    int i = blockIdx.x * blockDim.x + threadIdx.x;
    if (i < e) atomicAdd(&deg[dst[i]], 1.0f);
}
__global__ void f_finish_deg_g1(const float* __restrict__ x, float* __restrict__ dinv,
                                float* __restrict__ g1, int n) {
    int i = blockIdx.x * blockDim.x + threadIdx.x;
    if (i >= n) return;
    float d = rsqrtf(dinv[i]);
    dinv[i] = d;
#pragma unroll
    for (int f = 0; f < FIN; ++f) g1[(size_t)i * FIN + f] = x[(size_t)i * FIN + f] * d;
}
__global__ void f_scatter5(const int* __restrict__ src, const int* __restrict__ dst,
                           const float* __restrict__ g, float* __restrict__ acc, int e) {
    int i = blockIdx.x * blockDim.x + threadIdx.x;
    if (i >= e) return;
    int s = src[i], d = dst[i];
    float* a = acc + (size_t)d * 5;
    const float* gp = g + (size_t)s * 5;
    atomicAdd(a + 0, gp[0]);
    atomicAdd(a + 1, gp[1]);
    atomicAdd(a + 2, gp[2]);
    atomicAdd(a + 3, gp[3]);
    atomicAdd(a + 4, gp[4]);
}
__global__ void f_update1(const float* __restrict__ dinv, float* __restrict__ g,
                          float* __restrict__ acc, const float* __restrict__ W1,
                          const float* __restrict__ b1, int n) {
    int i = blockIdx.x * blockDim.x + threadIdx.x;
    if (i >= n) return;
    float d = dinv[i];
    float v[FIN];
#pragma unroll
    for (int f = 0; f < FIN; ++f) {
        size_t idx = (size_t)i * FIN + f;
        v[f] = (acc[idx] + g[idx]) * d;
        acc[idx] = 0.0f;
    }
#pragma unroll
    for (int j = 0; j < FHID; ++j) {
        float s = b1[j];
#pragma unroll
        for (int k = 0; k < FIN; ++k) s += v[k] * W1[k * FHID + j];
        g[(size_t)i * FHID + j] = fmaxf(s, 0.0f) * d;
    }
}
__global__ void f_update2(const float* __restrict__ dinv, const float* __restrict__ g,
                          const float* __restrict__ acc, const float* __restrict__ W2,
                          const float* __restrict__ b2, float* __restrict__ out, int n) {
    int i = blockIdx.x * blockDim.x + threadIdx.x;
    if (i >= n) return;
    float d = dinv[i];
    float v[FHID];
#pragma unroll
    for (int f = 0; f < FHID; ++f) v[f] = (acc[(size_t)i * FHID + f] + g[(size_t)i * FHID + f]) * d;
    float o[FOUT];
    float m = -1e30f;
#pragma unroll
    for (int j = 0; j < FOUT; ++j) {
        float s = b2[j];
#pragma unroll
        for (int k = 0; k < FHID; ++k) s += v[k] * W2[k * FOUT + j];
        o[j] = s;
        m = fmaxf(m, s);
    }
    float ssum = 0.0f;
#pragma unroll
    for (int j = 0; j < FOUT; ++j) ssum += expf(o[j] - m);
    float lse = m + logf(ssum);
#pragma unroll
    for (int j = 0; j < FOUT; ++j) out[(size_t)i * FOUT + j] = o[j] - lse;
}

// ---------- launcher ----------

extern "C" void kernel_launch(void* const* d_in, const int* in_sizes, int n_in,
                              void* d_out, int out_size, void* d_ws, size_t ws_size,
                              hipStream_t stream) {
    const float* x  = (const float*)d_in[0];
    const int*   ei = (const int*)d_in[1];
    const float* W1 = (const float*)d_in[2];
    const float* b1 = (const float*)d_in[3];
    const float* W2 = (const float*)d_in[4];
    const float* b2 = (const float*)d_in[5];

    const int n = in_sizes[0] / FIN;   // 500,000
    const int e = in_sizes[1] / 2;     // 16,000,000
    const int* src = ei;
    const int* dst = ei + e;

    const int nbuck = (n + RB - 1) / RB;          // 1954
    const int nblkE = (e + EPB - 1) / EPB;        // 489
    const size_t m = (size_t)nbuck * nblkE;       // ~955k
    const int nsb = (int)((m + 255) / 256);

    size_t off = 0;
    auto alloc = [&](size_t bytes) { size_t o = off; off = (off + bytes + 15) & ~(size_t)15; return o; };
    int*          cnt     = (int*)((char*)d_ws + alloc(m * 4));
    int*          scn     = (int*)((char*)d_ws + alloc(m * 4));
    int*          part    = (int*)((char*)d_ws + alloc((size_t)nsb * 4));
    float*        dinv    = (float*)((char*)d_ws + alloc((size_t)n * 4));
    half8*        g1      = (half8*)((char*)d_ws + alloc((size_t)n * 16));
    half8*        g2      = (half8*)((char*)d_ws + alloc((size_t)n * 16));
    int*          nodeptr = (int*)((char*)d_ws + alloc((size_t)nbuck * RB * 4));
    unsigned int* binned  = (unsigned int*)((char*)d_ws + alloc((size_t)e * 4));
    const size_t need = off;

    if (ws_size >= need && n <= (1 << 24) && nbuck <= NBUCK_MAX) {
        k_binhist<<<nblkE, 1024, 0, stream>>>(dst, cnt, e, nbuck, nblkE);
        k_scan1<<<nsb, 256, 0, stream>>>(cnt, scn, part, (int)m);
        k_scan2<<<1, 256, 0, stream>>>(part, nsb);
        k_binscatter<<<nblkE, 1024, 0, stream>>>(src, dst, scn, part, binned, e, nbuck, nblkE);
        k_deg_dsort<<<nbuck, 256, 0, stream>>>(binned, scn, part, x, dinv, g1, nodeptr, n, e, nbuck, nblkE);
        const int ga = (int)(((size_t)n * 16 + 511) / 512);
        k_agg1<<<ga, 512, 0, stream>>>(binned, nodeptr, scn, part, g1, dinv, W1, b1, g2, n, e, nbuck, nblkE);
        k_agg2<<<ga, 512, 0, stream>>>(binned, nodeptr, scn, part, g2, dinv, W2, b2, (float*)d_out, n, e, nbuck, nblkE);
    } else {
        const int B = 256;
        const int gn = (n + B - 1) / B;
        const int ge = (e + B - 1) / B;
        float* fdinv = (float*)d_ws;
        float* fg    = fdinv + n;
        float* facc  = fg + (size_t)5 * n;
        hipMemsetAsync(facc, 0, (size_t)5 * n * sizeof(float), stream);
        f_init_deg<<<gn, B, 0, stream>>>(fdinv, n);
        f_count_deg<<<ge, B, 0, stream>>>(dst, fdinv, e);
        f_finish_deg_g1<<<gn, B, 0, stream>>>(x, fdinv, fg, n);
        f_scatter5<<<ge, B, 0, stream>>>(src, dst, fg, facc, e);
        f_update1<<<gn, B, 0, stream>>>(fdinv, fg, facc, W1, b1, n);
        f_scatter5<<<ge, B, 0, stream>>>(src, dst, fg, facc, e);
        f_update2<<<gn, B, 0, stream>>>(fdinv, fg, facc, W2, b2, (float*)d_out, n);
    }
}

// Round 8
// 776.517 us; speedup vs baseline: 2.1409x; 1.0385x over previous
//
#include <hip/hip_runtime.h>
#include <math.h>

// GCN 2-layer, N=500k, E=16M, F 5->5->8.
// R8: two-level binning.
//   Level A: coarse buckets of 2048 nodes (NC=245): scatter runs lengthen
//     17 -> 134 edges (full 64B lines), LDS cursors 1 KB.
//   Level B (k_passB, 1 block per coarse bucket): per-node counts fit LDS ->
//     fused fine-hist + scan + nodeptr/dinv/g1 + node-sorted permute into a
//     256 KB L2-resident window. Eliminates deg_dsort and SORT_CAP entirely.
//   Aggs: R7's 16-lane shfl form, src-only edges, dinv folded into g1[5].
// Fallback: complete R7 pipeline if ws too small (ws >= 118 MB proven by R2).

#define FIN 5
#define FHID 5
#define FOUT 8
#define EPA 32768     // edges per level-A block
// R7 fallback params
#define RB 256
#define EPB 32768
#define NBUCK_MAX 2048
#define SORT_CAP 12288

typedef _Float16 half8 __attribute__((ext_vector_type(8)));
typedef int int4v __attribute__((ext_vector_type(4)));

// ================= shared scan kernels =================

__global__ void k_scan1(const int* __restrict__ t, int* __restrict__ scn,
                        int* __restrict__ partial, int n) {
    __shared__ int sh[256];
    int tx = threadIdx.x;
    int i = blockIdx.x * 256 + tx;
    int v = (i < n) ? t[i] : 0;
    sh[tx] = v;
    __syncthreads();
    for (int off = 1; off < 256; off <<= 1) {
        int add = (tx >= off) ? sh[tx - off] : 0;
        __syncthreads();
        sh[tx] += add;
        __syncthreads();
    }
    if (i < n) scn[i] = sh[tx] - v;
    if (tx == 255) partial[blockIdx.x] = sh[255];
}

__global__ void k_scan2(int* __restrict__ partial, int nb) {
    __shared__ int sh[256];
    __shared__ int carry;
    int tx = threadIdx.x;
    if (tx == 0) carry = 0;
    __syncthreads();
    for (int base = 0; base < nb; base += 256) {
        int i = base + tx;
        int v = (i < nb) ? partial[i] : 0;
        int c0 = carry;
        sh[tx] = v;
        __syncthreads();
        for (int off = 1; off < 256; off <<= 1) {
            int add = (tx >= off) ? sh[tx - off] : 0;
            __syncthreads();
            sh[tx] += add;
            __syncthreads();
        }
        if (i < nb) partial[i] = c0 + sh[tx] - v;
        __syncthreads();
        if (tx == 0) carry = c0 + sh[255];
        __syncthreads();
    }
}

// ================= v8 main path =================

__global__ void k_histA(const int* __restrict__ dst, int* __restrict__ cnt,
                        int e, int NC, int nblkA) {
    __shared__ int hist[256];
    int tx = threadIdx.x, blk = blockIdx.x;
    if (tx < 256) hist[tx] = 0;
    __syncthreads();
    size_t base = (size_t)blk * EPA;
    const int4v* dst4 = (const int4v*)dst;
    for (int k = 0; k < EPA / 4096; ++k) {
        size_t e4 = base / 4 + (size_t)k * 1024 + tx;
        size_t i = e4 * 4;
        if (i + 3 < (size_t)e) {
            int4v d4 = __builtin_nontemporal_load(&dst4[e4]);
#pragma unroll
            for (int j = 0; j < 4; ++j) atomicAdd(&hist[d4[j] >> 11], 1);
        } else {
            for (int j = 0; j < 4; ++j) {
                size_t ii = i + j;
                if (ii < (size_t)e) atomicAdd(&hist[dst[ii] >> 11], 1);
            }
        }
    }
    __syncthreads();
    if (tx < NC) cnt[(size_t)tx * nblkA + blk] = hist[tx];
}

__global__ void k_scatterA(const int* __restrict__ src, const int* __restrict__ dst,
                           const int* __restrict__ scn, const int* __restrict__ part,
                           unsigned int* __restrict__ binnedA,
                           int e, int NC, int nblkA) {
    __shared__ int cur[256];
    int tx = threadIdx.x, blk = blockIdx.x;
    if (tx < NC) {
        size_t idx = (size_t)tx * nblkA + blk;
        cur[tx] = scn[idx] + part[idx >> 8];
    }
    __syncthreads();
    size_t base = (size_t)blk * EPA;
    const int4v* dst4 = (const int4v*)dst;
    const int4v* src4 = (const int4v*)src;
    for (int k = 0; k < EPA / 4096; ++k) {
        size_t e4 = base / 4 + (size_t)k * 1024 + tx;
        size_t i = e4 * 4;
        if (i + 3 < (size_t)e) {
            int4v d4 = __builtin_nontemporal_load(&dst4[e4]);
            int4v s4 = __builtin_nontemporal_load(&src4[e4]);
#pragma unroll
            for (int j = 0; j < 4; ++j) {
                int d = d4[j];
                int pos = atomicAdd(&cur[d >> 11], 1);
                binnedA[pos] = ((unsigned int)(d & 2047) << 19) | (unsigned int)s4[j];
            }
        } else {
            for (int j = 0; j < 4; ++j) {
                size_t ii = i + j;
                if (ii < (size_t)e) {
                    int d = dst[ii];
                    int pos = atomicAdd(&cur[d >> 11], 1);
                    binnedA[pos] = ((unsigned int)(d & 2047) << 19) | (unsigned int)src[ii];
                }
            }
        }
    }
}

// one block per coarse bucket: per-node hist -> scan -> nodeptr/dinv/g1,
// then node-sorted permute (src-only) into binned2 (L2-local window).
__global__ void k_passB(const unsigned int* __restrict__ binnedA,
                        const int* __restrict__ scn, const int* __restrict__ part,
                        const float* __restrict__ x,
                        half8* __restrict__ g1, unsigned int* __restrict__ binned2,
                        int* __restrict__ nodeptr,
                        int n, int e, int NC, int nblkA) {
    __shared__ int cnt2[2048];
    __shared__ int sA[2048];
    __shared__ int sB[2048];
    __shared__ int cur2[2048];
    int tx = threadIdx.x, b = blockIdx.x;
    cnt2[tx] = 0; cnt2[tx + 1024] = 0;
    __syncthreads();
    size_t i0 = (size_t)b * nblkA;
    int cstart = scn[i0] + part[i0 >> 8];
    int cend;
    if (b + 1 < NC) {
        size_t i1 = (size_t)(b + 1) * nblkA;
        cend = scn[i1] + part[i1 >> 8];
    } else {
        cend = e;
    }
    // phase 1: per-node counts
    for (int i = cstart + tx; i < cend; i += 1024) {
        unsigned int p = __builtin_nontemporal_load(&binnedA[i]);
        atomicAdd(&cnt2[p >> 19], 1);
    }
    __syncthreads();
    // inclusive scan of cnt2 (Hillis-Steele ping-pong, 2 elems/thread)
    sA[tx] = cnt2[tx]; sA[tx + 1024] = cnt2[tx + 1024];
    __syncthreads();
    int* pin = sA; int* pout = sB;
    for (int off = 1; off < 2048; off <<= 1) {
        for (int j = tx; j < 2048; j += 1024) {
            int v = pin[j];
            if (j >= off) v += pin[j - off];
            pout[j] = v;
        }
        __syncthreads();
        int* t = pin; pin = pout; pout = t;
    }
    // nodeptr, cursors, dinv+g1
#pragma unroll
    for (int h = 0; h < 2; ++h) {
        int l = tx + h * 1024;
        int abs0 = cstart + pin[l] - cnt2[l];
        nodeptr[((size_t)b << 11) + l] = abs0;
        cur2[l] = abs0;
        int node = (b << 11) + l;
        if (node < n) {
            float d = rsqrtf((float)(cnt2[l] + 1));  // +1 self-loop
            const float* xp = x + (size_t)node * FIN;
            half8 row = {};
#pragma unroll
            for (int f = 0; f < FIN; ++f) row[f] = (_Float16)(xp[f] * d);
            row[5] = (_Float16)d;                    // dinv folded into slot 5
            g1[node] = row;
        }
    }
    if (b == NC - 1 && tx == 0) nodeptr[(size_t)NC << 11] = cend;
    __syncthreads();
    // phase 2: permute into node order, store src only
    for (int i = cstart + tx; i < cend; i += 1024) {
        unsigned int p = binnedA[i];
        int pos = atomicAdd(&cur2[p >> 19], 1);
        binned2[pos] = p & 0x7FFFFu;
    }
}

// layer 1: 16 lanes/node, register accumulate, shfl reduce, fused W1+relu
__global__ void k_vagg1(const unsigned int* __restrict__ ed,
                        const int* __restrict__ nodeptr,
                        const half8* __restrict__ g1,
                        const float* __restrict__ W1, const float* __restrict__ b1,
                        half8* __restrict__ g2, int n) {
    int tid = blockIdx.x * blockDim.x + threadIdx.x;
    int node = tid >> 4;
    int lane = tid & 15;
    if (node >= n) return;
    int o0 = nodeptr[node];
    int o1 = nodeptr[node + 1];
    float a0 = 0, a1 = 0, a2 = 0, a3 = 0, a4 = 0;
    for (int k = o0 + lane; k < o1; k += 16) {
        unsigned int s = __builtin_nontemporal_load(&ed[k]);
        half8 hv = g1[s];
        a0 += (float)hv[0]; a1 += (float)hv[1]; a2 += (float)hv[2];
        a3 += (float)hv[3]; a4 += (float)hv[4];
    }
#pragma unroll
    for (int off = 1; off < 16; off <<= 1) {
        a0 += __shfl_xor(a0, off, 16);
        a1 += __shfl_xor(a1, off, 16);
        a2 += __shfl_xor(a2, off, 16);
        a3 += __shfl_xor(a3, off, 16);
        a4 += __shfl_xor(a4, off, 16);
    }
    if (lane == 0) {
        half8 gi = g1[node];
        float d = (float)gi[5];
        float v[FIN];
        v[0] = (a0 + (float)gi[0]) * d;
        v[1] = (a1 + (float)gi[1]) * d;
        v[2] = (a2 + (float)gi[2]) * d;
        v[3] = (a3 + (float)gi[3]) * d;
        v[4] = (a4 + (float)gi[4]) * d;
        half8 go = {};
#pragma unroll
        for (int j = 0; j < FHID; ++j) {
            float s = b1[j];
#pragma unroll
            for (int k = 0; k < FIN; ++k) s = fmaf(v[k], W1[k * FHID + j], s);
            go[j] = (_Float16)(fmaxf(s, 0.0f) * d);  // relu, pre-scaled
        }
        go[5] = gi[5];                               // carry dinv forward
        g2[node] = go;
    }
}

// layer 2: same + fused W2 + log_softmax
__global__ void k_vagg2(const unsigned int* __restrict__ ed,
                        const int* __restrict__ nodeptr,
                        const half8* __restrict__ g2,
                        const float* __restrict__ W2, const float* __restrict__ b2,
                        float* __restrict__ out, int n) {
    int tid = blockIdx.x * blockDim.x + threadIdx.x;
    int node = tid >> 4;
    int lane = tid & 15;
    if (node >= n) return;
    int o0 = nodeptr[node];
    int o1 = nodeptr[node + 1];
    float a0 = 0, a1 = 0, a2 = 0, a3 = 0, a4 = 0;
    for (int k = o0 + lane; k < o1; k += 16) {
        unsigned int s = __builtin_nontemporal_load(&ed[k]);
        half8 hv = g2[s];
        a0 += (float)hv[0]; a1 += (float)hv[1]; a2 += (float)hv[2];
        a3 += (float)hv[3]; a4 += (float)hv[4];
    }
#pragma unroll
    for (int off = 1; off < 16; off <<= 1) {
        a0 += __shfl_xor(a0, off, 16);
        a1 += __shfl_xor(a1, off, 16);
        a2 += __shfl_xor(a2, off, 16);
        a3 += __shfl_xor(a3, off, 16);
        a4 += __shfl_xor(a4, off, 16);
    }
    if (lane == 0) {
        half8 gi = g2[node];
        float d = (float)gi[5];
        float v[FHID];
        v[0] = (a0 + (float)gi[0]) * d;
        v[1] = (a1 + (float)gi[1]) * d;
        v[2] = (a2 + (float)gi[2]) * d;
        v[3] = (a3 + (float)gi[3]) * d;
        v[4] = (a4 + (float)gi[4]) * d;
        float o[FOUT];
        float m = -1e30f;
#pragma unroll
        for (int j = 0; j < FOUT; ++j) {
            float s = b2[j];
#pragma unroll
            for (int k = 0; k < FHID; ++k) s = fmaf(v[k], W2[k * FOUT + j], s);
            o[j] = s;
            m = fmaxf(m, s);
        }
        float ssum = 0.0f;
#pragma unroll
        for (int j = 0; j < FOUT; ++j) ssum += expf(o[j] - m);
        float lse = m + logf(ssum);
        float* op = out + (size_t)node * FOUT;
#pragma unroll
        for (int j = 0; j < FOUT; ++j) op[j] = o[j] - lse;
    }
}

// ================= R7 fallback path =================

__global__ void r7_binhist(const int* __restrict__ dst, int* __restrict__ cnt,
                           int e, int nbuck, int nblkE) {
    __shared__ int hist[NBUCK_MAX];
    int tx = threadIdx.x, blk = blockIdx.x;
    for (int b = tx; b < nbuck; b += 1024) hist[b] = 0;
    __syncthreads();
    size_t base = (size_t)blk * EPB;
    for (int k = 0; k < EPB; k += 4096) {
        size_t i0 = base + k + tx;
        int d0 = (i0 < (size_t)e) ? __builtin_nontemporal_load(&dst[i0]) : -1;
        int d1 = (i0 + 1024 < (size_t)e) ? __builtin_nontemporal_load(&dst[i0 + 1024]) : -1;
        int d2 = (i0 + 2048 < (size_t)e) ? __builtin_nontemporal_load(&dst[i0 + 2048]) : -1;
        int d3 = (i0 + 3072 < (size_t)e) ? __builtin_nontemporal_load(&dst[i0 + 3072]) : -1;
        if (d0 >= 0) atomicAdd(&hist[d0 >> 8], 1);
        if (d1 >= 0) atomicAdd(&hist[d1 >> 8], 1);
        if (d2 >= 0) atomicAdd(&hist[d2 >> 8], 1);
        if (d3 >= 0) atomicAdd(&hist[d3 >> 8], 1);
    }
    __syncthreads();
    for (int b = tx; b < nbuck; b += 1024) cnt[(size_t)b * nblkE + blk] = hist[b];
}

__global__ void r7_binscatter(const int* __restrict__ src, const int* __restrict__ dst,
                              const int* __restrict__ scn, const int* __restrict__ part,
                              unsigned int* __restrict__ binned,
                              int e, int nbuck, int nblkE) {
    __shared__ int cur[NBUCK_MAX];
    int tx = threadIdx.x, blk = blockIdx.x;
    for (int b = tx; b < nbuck; b += 1024) {
        size_t idx = (size_t)b * nblkE + blk;
        cur[b] = scn[idx] + part[idx >> 8];
    }
    __syncthreads();
    size_t base = (size_t)blk * EPB;
    for (int k = 0; k < EPB; k += 4096) {
        size_t i0 = base + k + tx;
        int d0 = (i0 < (size_t)e) ? __builtin_nontemporal_load(&dst[i0]) : -1;
        int d1 = (i0 + 1024 < (size_t)e) ? __builtin_nontemporal_load(&dst[i0 + 1024]) : -1;
        int d2 = (i0 + 2048 < (size_t)e) ? __builtin_nontemporal_load(&dst[i0 + 2048]) : -1;
        int d3 = (i0 + 3072 < (size_t)e) ? __builtin_nontemporal_load(&dst[i0 + 3072]) : -1;
        int s0 = (d0 >= 0) ? __builtin_nontemporal_load(&src[i0]) : 0;
        int s1 = (d1 >= 0) ? __builtin_nontemporal_load(&src[i0 + 1024]) : 0;
        int s2 = (d2 >= 0) ? __builtin_nontemporal_load(&src[i0 + 2048]) : 0;
        int s3 = (d3 >= 0) ? __builtin_nontemporal_load(&src[i0 + 3072]) : 0;
        if (d0 >= 0) { int p = atomicAdd(&cur[d0 >> 8], 1);
            binned[p] = ((unsigned int)(d0 & (RB - 1)) << 24) | (unsigned int)s0; }
        if (d1 >= 0) { int p = atomicAdd(&cur[d1 >> 8], 1);
            binned[p] = ((unsigned int)(d1 & (RB - 1)) << 24) | (unsigned int)s1; }
        if (d2 >= 0) { int p = atomicAdd(&cur[d2 >> 8], 1);
            binned[p] = ((unsigned int)(d2 & (RB - 1)) << 24) | (unsigned int)s2; }
        if (d3 >= 0) { int p = atomicAdd(&cur[d3 >> 8], 1);
            binned[p] = ((unsigned int)(d3 & (RB - 1)) << 24) | (unsigned int)s3; }
    }
}

__device__ __forceinline__ void r7_range(const int* __restrict__ scn,
                                         const int* __restrict__ part,
                                         int b, int nbuck, int nblkE, int e,
                                         int& start, int& end) {
    size_t i0 = (size_t)b * nblkE;
    start = scn[i0] + part[i0 >> 8];
    if (b + 1 < nbuck) {
        size_t i1 = (size_t)(b + 1) * nblkE;
        end = scn[i1] + part[i1 >> 8];
    } else {
        end = e;
    }
}

__global__ void r7_deg_dsort(unsigned int* __restrict__ binned,
                             const int* __restrict__ scn, const int* __restrict__ part,
                             const float* __restrict__ x, float* __restrict__ dinv,
                             half8* __restrict__ g1, int* __restrict__ nodeptr,
                             int n, int e, int nbuck, int nblkE) {
    __shared__ unsigned int buf[SORT_CAP];
    __shared__ int cnt[RB];
    __shared__ int sh[RB];
    __shared__ int base[RB];
    int tx = threadIdx.x, b = blockIdx.x;
    cnt[tx] = 0;
    __syncthreads();
    int start, end;
    r7_range(scn, part, b, nbuck, nblkE, e, start, end);
    int len = end - start;
    bool stage = (len <= SORT_CAP);
    for (int i = tx; i < len; i += 256) {
        unsigned int p = binned[start + i];
        atomicAdd(&cnt[p >> 24], 1);
        if (stage) buf[i] = p;
    }
    __syncthreads();
    int v = cnt[tx];
    sh[tx] = v;
    __syncthreads();
    for (int off = 1; off < 256; off <<= 1) {
        int add = (tx >= off) ? sh[tx - off] : 0;
        __syncthreads();
        sh[tx] += add;
        __syncthreads();
    }
    int excl = sh[tx] - v;
    nodeptr[(size_t)b * RB + tx] = stage ? (start + excl) : -1;
    base[tx] = excl;
    __syncthreads();
    if (stage) {
        for (int i = tx; i < len; i += 256) {
            unsigned int p = buf[i];
            int pos = atomicAdd(&base[p >> 24], 1);
            binned[start + pos] = p;
        }
    }
    int node = b * RB + tx;
    if (node < n) {
        float d = rsqrtf((float)(cnt[tx] + 1));
        dinv[node] = d;
        const float* xp = x + (size_t)node * FIN;
        half8 row = {};
#pragma unroll
        for (int f = 0; f < FIN; ++f) row[f] = (_Float16)(xp[f] * d);
        g1[node] = row;
    }
}

__global__ void r7_agg1(const unsigned int* __restrict__ binned,
                        const int* __restrict__ nodeptr,
                        const int* __restrict__ scn, const int* __restrict__ part,
                        const half8* __restrict__ g1, const float* __restrict__ dinv,
                        const float* __restrict__ W1, const float* __restrict__ b1,
                        half8* __restrict__ g2, int n, int e, int nbuck, int nblkE) {
    int tid = blockIdx.x * blockDim.x + threadIdx.x;
    int node = tid >> 4;
    int lane = tid & 15;
    if (node >= n) return;
    int o0 = nodeptr[node];
    float a0 = 0, a1 = 0, a2 = 0, a3 = 0, a4 = 0;
    if (o0 >= 0) {
        int b = node >> 8;
        int dl = node & (RB - 1);
        int o1;
        if (dl == RB - 1) { int s_, e_; r7_range(scn, part, b, nbuck, nblkE, e, s_, e_); o1 = e_; }
        else o1 = nodeptr[node + 1];
        for (int k = o0 + lane; k < o1; k += 16) {
            unsigned int p = __builtin_nontemporal_load(&binned[k]);
            half8 hv = g1[p & 0xFFFFFF];
            a0 += (float)hv[0]; a1 += (float)hv[1]; a2 += (float)hv[2];
            a3 += (float)hv[3]; a4 += (float)hv[4];
        }
    } else {
        int b = node >> 8;
        int dl = node & (RB - 1);
        int s_, e_;
        r7_range(scn, part, b, nbuck, nblkE, e, s_, e_);
        for (int k = s_ + lane; k < e_; k += 16) {
            unsigned int p = binned[k];
            if ((int)(p >> 24) == dl) {
                half8 hv = g1[p & 0xFFFFFF];
                a0 += (float)hv[0]; a1 += (float)hv[1]; a2 += (float)hv[2];
                a3 += (float)hv[3]; a4 += (float)hv[4];
            }
        }
    }
#pragma unroll
    for (int off = 1; off < 16; off <<= 1) {
        a0 += __shfl_xor(a0, off, 16);
        a1 += __shfl_xor(a1, off, 16);
        a2 += __shfl_xor(a2, off, 16);
        a3 += __shfl_xor(a3, off, 16);
        a4 += __shfl_xor(a4, off, 16);
    }
    if (lane == 0) {
        float d = dinv[node];
        half8 gi = g1[node];
        float v[FIN];
        v[0] = (a0 + (float)gi[0]) * d;
        v[1] = (a1 + (float)gi[1]) * d;
        v[2] = (a2 + (float)gi[2]) * d;
        v[3] = (a3 + (float)gi[3]) * d;
        v[4] = (a4 + (float)gi[4]) * d;
        half8 go = {};
#pragma unroll
        for (int j = 0; j < FHID; ++j) {
            float s = b1[j];
#pragma unroll
            for (int k = 0; k < FIN; ++k) s = fmaf(v[k], W1[k * FHID + j], s);
            go[j] = (_Float16)(fmaxf(s, 0.0f) * d);
        }
        g2[node] = go;
    }
}

__global__ void r7_agg2(const unsigned int* __restrict__ binned,
                        const int* __restrict__ nodeptr,
                        const int* __restrict__ scn, const int* __restrict__ part,
                        const half8* __restrict__ g2, const float* __restrict__ dinv,
                        const float* __restrict__ W2, const float* __restrict__ b2,
                        float* __restrict__ out, int n, int e, int nbuck, int nblkE) {
    int tid = blockIdx.x * blockDim.x + threadIdx.x;
    int node = tid >> 4;
    int lane = tid & 15;
    if (node >= n) return;
    int o0 = nodeptr[node];
    float a0 = 0, a1 = 0, a2 = 0, a3 = 0, a4 = 0;
    if (o0 >= 0) {
        int b = node >> 8;
        int dl = node & (RB - 1);
        int o1;
        if (dl == RB - 1) { int s_, e_; r7_range(scn, part, b, nbuck, nblkE, e, s_, e_); o1 = e_; }
        else o1 = nodeptr[node + 1];
        for (int k = o0 + lane; k < o1; k += 16) {
            unsigned int p = __builtin_nontemporal_load(&binned[k]);
            half8 hv = g2[p & 0xFFFFFF];
            a0 += (float)hv[0]; a1 += (float)hv[1]; a2 += (float)hv[2];
            a3 += (float)hv[3]; a4 += (float)hv[4];
        }
    } else {
        int b = node >> 8;
        int dl = node & (RB - 1);
        int s_, e_;
        r7_range(scn, part, b, nbuck, nblkE, e, s_, e_);
        for (int k = s_ + lane; k < e_; k += 16) {
            unsigned int p = binned[k];
            if ((int)(p >> 24) == dl) {
                half8 hv = g2[p & 0xFFFFFF];
                a0 += (float)hv[0]; a1 += (float)hv[1]; a2 += (float)hv[2];
                a3 += (float)hv[3]; a4 += (float)hv[4];
            }
        }
    }
#pragma unroll
    for (int off = 1; off < 16; off <<= 1) {
        a0 += __shfl_xor(a0, off, 16);
        a1 += __shfl_xor(a1, off, 16);
        a2 += __shfl_xor(a2, off, 16);
        a3 += __shfl_xor(a3, off, 16);
        a4 += __shfl_xor(a4, off, 16);
    }
    if (lane == 0) {
        float d = dinv[node];
        half8 gi = g2[node];
        float v[FHID];
        v[0] = (a0 + (float)gi[0]) * d;
        v[1] = (a1 + (float)gi[1]) * d;
        v[2] = (a2 + (float)gi[2]) * d;
        v[3] = (a3 + (float)gi[3]) * d;
        v[4] = (a4 + (float)gi[4]) * d;
        float o[FOUT];
        float m = -1e30f;
#pragma unroll
        for (int j = 0; j < FOUT; ++j) {
            float s = b2[j];
#pragma unroll
            for (int k = 0; k < FHID; ++k) s = fmaf(v[k], W2[k * FOUT + j], s);
            o[j] = s;
            m = fmaxf(m, s);
        }
        float ssum = 0.0f;
#pragma unroll
        for (int j = 0; j < FOUT; ++j) ssum += expf(o[j] - m);
        float lse = m + logf(ssum);
        float* op = out + (size_t)node * FOUT;
#pragma unroll
        for (int j = 0; j < FOUT; ++j) op[j] = o[j] - lse;
    }
}

// ================= launcher =================

extern "C" void kernel_launch(void* const* d_in, const int* in_sizes, int n_in,
                              void* d_out, int out_size, void* d_ws, size_t ws_size,
                              hipStream_t stream) {
    const float* x  = (const float*)d_in[0];
    const int*   ei = (const int*)d_in[1];
    const float* W1 = (const float*)d_in[2];
    const float* b1 = (const float*)d_in[3];
    const float* W2 = (const float*)d_in[4];
    const float* b2 = (const float*)d_in[5];

    const int n = in_sizes[0] / FIN;   // 500,000
    const int e = in_sizes[1] / 2;     // 16,000,000
    const int* src = ei;
    const int* dst = ei + e;

    // ---- v8 layout ----
    const int NC = (n + 2047) >> 11;              // 245 coarse buckets
    const int nblkA = (e + EPA - 1) / EPA;        // 489
    const size_t m8 = (size_t)NC * nblkA;
    const int nsb8 = (int)((m8 + 255) / 256);
    size_t off8 = 0;
    auto al8 = [&](size_t bytes) { size_t o = off8; off8 = (off8 + bytes + 15) & ~(size_t)15; return o; };
    int*          cnt8    = (int*)((char*)d_ws + al8(m8 * 4));
    int*          scn8    = (int*)((char*)d_ws + al8(m8 * 4));
    int*          part8   = (int*)((char*)d_ws + al8((size_t)nsb8 * 4));
    int*          nptr8   = (int*)((char*)d_ws + al8(((size_t)NC * 2048 + 1) * 4));
    half8*        g1_8    = (half8*)((char*)d_ws + al8((size_t)n * 16));
    unsigned int* binnedA = (unsigned int*)((char*)d_ws + al8((size_t)e * 4));
    unsigned int* binned2 = (unsigned int*)((char*)d_ws + al8((size_t)e * 4));
    half8*        g2_8    = (half8*)binnedA;      // binnedA dead after passB
    const size_t need8 = off8;

    if (ws_size >= need8 && n <= 524288 && n >= 1 && (e & 3) == 0 && NC <= 256) {
        k_histA<<<nblkA, 1024, 0, stream>>>(dst, cnt8, e, NC, nblkA);
        k_scan1<<<nsb8, 256, 0, stream>>>(cnt8, scn8, part8, (int)m8);
        k_scan2<<<1, 256, 0, stream>>>(part8, nsb8);
        k_scatterA<<<nblkA, 1024, 0, stream>>>(src, dst, scn8, part8, binnedA, e, NC, nblkA);
        k_passB<<<NC, 1024, 0, stream>>>(binnedA, scn8, part8, x, g1_8, binned2, nptr8, n, e, NC, nblkA);
        const int ga = (int)(((size_t)n * 16 + 511) / 512);
        k_vagg1<<<ga, 512, 0, stream>>>(binned2, nptr8, g1_8, W1, b1, g2_8, n);
        k_vagg2<<<ga, 512, 0, stream>>>(binned2, nptr8, g2_8, W2, b2, (float*)d_out, n);
        return;
    }

    // ---- R7 fallback ----
    const int nbuck = (n + RB - 1) / RB;
    const int nblkE = (e + EPB - 1) / EPB;
    const size_t m7 = (size_t)nbuck * nblkE;
    const int nsb7 = (int)((m7 + 255) / 256);
    size_t off7 = 0;
    auto al7 = [&](size_t bytes) { size_t o = off7; off7 = (off7 + bytes + 15) & ~(size_t)15; return o; };
    int*          cnt7    = (int*)((char*)d_ws + al7(m7 * 4));
    int*          scn7    = (int*)((char*)d_ws + al7(m7 * 4));
    int*          part7   = (int*)((char*)d_ws + al7((size_t)nsb7 * 4));
    float*        dinv7   = (float*)((char*)d_ws + al7((size_t)n * 4));
    half8*        g1_7    = (half8*)((char*)d_ws + al7((size_t)n * 16));
    half8*        g2_7    = (half8*)((char*)d_ws + al7((size_t)n * 16));
    int*          nptr7   = (int*)((char*)d_ws + al7((size_t)nbuck * RB * 4));
    unsigned int* binned7 = (unsigned int*)((char*)d_ws + al7((size_t)e * 4));

    r7_binhist<<<nblkE, 1024, 0, stream>>>(dst, cnt7, e, nbuck, nblkE);
    k_scan1<<<nsb7, 256, 0, stream>>>(cnt7, scn7, part7, (int)m7);
    k_scan2<<<1, 256, 0, stream>>>(part7, nsb7);
    r7_binscatter<<<nblkE, 1024, 0, stream>>>(src, dst, scn7, part7, binned7, e, nbuck, nblkE);
    r7_deg_dsort<<<nbuck, 256, 0, stream>>>(binned7, scn7, part7, x, dinv7, g1_7, nptr7, n, e, nbuck, nblkE);
    const int ga7 = (int)(((size_t)n * 16 + 511) / 512);
    r7_agg1<<<ga7, 512, 0, stream>>>(binned7, nptr7, scn7, part7, g1_7, dinv7, W1, b1, g2_7, n, e, nbuck, nblkE);
    r7_agg2<<<ga7, 512, 0, stream>>>(binned7, nptr7, scn7, part7, g2_7, dinv7, W2, b2, (float*)d_out, n, e, nbuck, nblkE);
}

// Round 9
// 733.745 us; speedup vs baseline: 2.2657x; 1.0583x over previous
//
#include <hip/hip_runtime.h>
#include <math.h>

// GCN 2-layer, N=500k, E=16M, F 5->5->8.
// R9: scattered-GLOBAL-store floor (~12 cyc/edge, R7/R8 evidence) is paid once
//     instead of twice: passB's permute is replaced by k_passC, an LDS-staged
//     counting sort per 256-node bucket (scattered writes go to LDS obuf,
//     global output is a coalesced 64 MB stream). scatterA back to 1954 fine
//     buckets; edges packed (dl 8b | src 19b). nodeptr/dinv/g1 fused in passC.
// Fallback: R1 atomic-scatter path if ws/shape limits exceeded.

#define FIN 5
#define FHID 5
#define FOUT 8
#define RB 256        // nodes per bucket
#define EPA 32768     // edges per level-A block
#define NBUCK_MAX 2048
#define OCAP 10240    // LDS staging cap (mean 8188 + 22 sigma), 40 KB

typedef _Float16 half8 __attribute__((ext_vector_type(8)));
typedef int int4v __attribute__((ext_vector_type(4)));

// ---------------- scans ----------------

__global__ void k_scan1(const int* __restrict__ t, int* __restrict__ scn,
                        int* __restrict__ partial, int n) {
    __shared__ int sh[256];
    int tx = threadIdx.x;
    int i = blockIdx.x * 256 + tx;
    int v = (i < n) ? t[i] : 0;
    sh[tx] = v;
    __syncthreads();
    for (int off = 1; off < 256; off <<= 1) {
        int add = (tx >= off) ? sh[tx - off] : 0;
        __syncthreads();
        sh[tx] += add;
        __syncthreads();
    }
    if (i < n) scn[i] = sh[tx] - v;
    if (tx == 255) partial[blockIdx.x] = sh[255];
}

__global__ void k_scan2(int* __restrict__ partial, int nb) {
    __shared__ int sh[256];
    __shared__ int carry;
    int tx = threadIdx.x;
    if (tx == 0) carry = 0;
    __syncthreads();
    for (int base = 0; base < nb; base += 256) {
        int i = base + tx;
        int v = (i < nb) ? partial[i] : 0;
        int c0 = carry;
        sh[tx] = v;
        __syncthreads();
        for (int off = 1; off < 256; off <<= 1) {
            int add = (tx >= off) ? sh[tx - off] : 0;
            __syncthreads();
            sh[tx] += add;
            __syncthreads();
        }
        if (i < nb) partial[i] = c0 + sh[tx] - v;
        __syncthreads();
        if (tx == 0) carry = c0 + sh[255];
        __syncthreads();
    }
}

// ---------------- binning ----------------

__global__ void k_histA(const int* __restrict__ dst, int* __restrict__ cnt,
                        int e, int nbuck, int nblkA) {
    __shared__ int hist[NBUCK_MAX];
    int tx = threadIdx.x, blk = blockIdx.x;
    for (int b = tx; b < nbuck; b += 1024) hist[b] = 0;
    __syncthreads();
    size_t base = (size_t)blk * EPA;
    const int4v* dst4 = (const int4v*)dst;
    for (int k = 0; k < EPA / 4096; ++k) {
        size_t e4 = base / 4 + (size_t)k * 1024 + tx;
        size_t i = e4 * 4;
        if (i + 3 < (size_t)e) {
            int4v d4 = __builtin_nontemporal_load(&dst4[e4]);
#pragma unroll
            for (int j = 0; j < 4; ++j) atomicAdd(&hist[d4[j] >> 8], 1);
        } else {
            for (int j = 0; j < 4; ++j) {
                size_t ii = i + j;
                if (ii < (size_t)e) atomicAdd(&hist[dst[ii] >> 8], 1);
            }
        }
    }
    __syncthreads();
    for (int b = tx; b < nbuck; b += 1024) cnt[(size_t)b * nblkA + blk] = hist[b];
}

__global__ void k_scatterA(const int* __restrict__ src, const int* __restrict__ dst,
                           const int* __restrict__ scn, const int* __restrict__ part,
                           unsigned int* __restrict__ binnedA,
                           int e, int nbuck, int nblkA) {
    __shared__ int cur[NBUCK_MAX];
    int tx = threadIdx.x, blk = blockIdx.x;
    for (int b = tx; b < nbuck; b += 1024) {
        size_t idx = (size_t)b * nblkA + blk;
        cur[b] = scn[idx] + part[idx >> 8];
    }
    __syncthreads();
    size_t base = (size_t)blk * EPA;
    const int4v* dst4 = (const int4v*)dst;
    const int4v* src4 = (const int4v*)src;
    for (int k = 0; k < EPA / 4096; ++k) {
        size_t e4 = base / 4 + (size_t)k * 1024 + tx;
        size_t i = e4 * 4;
        if (i + 3 < (size_t)e) {
            int4v d4 = __builtin_nontemporal_load(&dst4[e4]);
            int4v s4 = __builtin_nontemporal_load(&src4[e4]);
#pragma unroll
            for (int j = 0; j < 4; ++j) {
                int d = d4[j];
                int pos = atomicAdd(&cur[d >> 8], 1);
                binnedA[pos] = ((unsigned int)(d & (RB - 1)) << 19) | (unsigned int)s4[j];
            }
        } else {
            for (int j = 0; j < 4; ++j) {
                size_t ii = i + j;
                if (ii < (size_t)e) {
                    int d = dst[ii];
                    int pos = atomicAdd(&cur[d >> 8], 1);
                    binnedA[pos] = ((unsigned int)(d & (RB - 1)) << 19) | (unsigned int)src[ii];
                }
            }
        }
    }
}

// ---------------- passC: LDS-staged node-sort + nodeptr + dinv + g1 ----------------

__global__ void k_passC(const unsigned int* __restrict__ binnedA,
                        const int* __restrict__ scn, const int* __restrict__ part,
                        const float* __restrict__ x,
                        half8* __restrict__ g1, unsigned int* __restrict__ binned3,
                        int* __restrict__ nodeptr,
                        int n, int e, int nbuck, int nblkA) {
    __shared__ int hist[RB];
    __shared__ int scanbuf[RB];
    __shared__ int cur[RB];
    __shared__ unsigned int obuf[OCAP];   // 40 KB
    int tx = threadIdx.x, b = blockIdx.x;
    if (tx < RB) hist[tx] = 0;
    __syncthreads();
    size_t i0 = (size_t)b * nblkA;
    int start = scn[i0] + part[i0 >> 8];
    int end;
    if (b + 1 < nbuck) {
        size_t i1 = (size_t)(b + 1) * nblkA;
        end = scn[i1] + part[i1 >> 8];
    } else {
        end = e;
    }
    int len = end - start;
    // phase 1: per-node hist (plain loads -> 2nd read is L2-hot)
    for (int i = start + tx; i < end; i += 512)
        atomicAdd(&hist[binnedA[i] >> 19], 1);
    __syncthreads();
    // block scan of 256 counts (tx<256 active, all threads hit barriers)
    int v = 0;
    if (tx < RB) { v = hist[tx]; scanbuf[tx] = v; }
    __syncthreads();
    for (int off = 1; off < RB; off <<= 1) {
        int add = 0;
        if (tx < RB && tx >= off) add = scanbuf[tx - off];
        __syncthreads();
        if (tx < RB) scanbuf[tx] += add;
        __syncthreads();
    }
    if (tx < RB) {
        int excl = scanbuf[tx] - v;
        nodeptr[(size_t)b * RB + tx] = start + excl;
        cur[tx] = excl;
        int node = b * RB + tx;
        if (node < n) {
            float d = rsqrtf((float)(v + 1));   // +1 self-loop
            const float* xp = x + (size_t)node * FIN;
            half8 row = {};
#pragma unroll
            for (int f = 0; f < FIN; ++f) row[f] = (_Float16)(xp[f] * d);
            row[5] = (_Float16)d;               // dinv folded into slot 5
            g1[node] = row;
        }
    }
    if (b == nbuck - 1 && tx == 0) nodeptr[(size_t)nbuck * RB] = end;
    __syncthreads();
    if (len <= OCAP) {
        // phase 2: permute into LDS (scattered LDS write ~free)
        for (int i = start + tx; i < end; i += 512) {
            unsigned int p = binnedA[i];
            int pos = atomicAdd(&cur[p >> 19], 1);
            obuf[pos] = p & 0x7FFFFu;
        }
        __syncthreads();
        // phase 3: coalesced flush
        for (int j = tx; j < len; j += 512)
            binned3[start + j] = obuf[j];
    } else {
        // overflow fallback: direct scattered global permute (correct, rare)
        for (int i = start + tx; i < end; i += 512) {
            unsigned int p = binnedA[i];
            int pos = atomicAdd(&cur[p >> 19], 1);
            binned3[start + pos] = p & 0x7FFFFu;
        }
    }
}

// ---------------- aggregation: 16 lanes/node, shfl reduce ----------------

__global__ void k_vagg1(const unsigned int* __restrict__ ed,
                        const int* __restrict__ nodeptr,
                        const half8* __restrict__ g1,
                        const float* __restrict__ W1, const float* __restrict__ b1,
                        half8* __restrict__ g2, int n) {
    int tid = blockIdx.x * blockDim.x + threadIdx.x;
    int node = tid >> 4;
    int lane = tid & 15;
    if (node >= n) return;
    int o0 = nodeptr[node];
    int o1 = nodeptr[node + 1];
    float a0 = 0, a1 = 0, a2 = 0, a3 = 0, a4 = 0;
    for (int k = o0 + lane; k < o1; k += 16) {
        unsigned int s = __builtin_nontemporal_load(&ed[k]);
        half8 hv = g1[s];
        a0 += (float)hv[0]; a1 += (float)hv[1]; a2 += (float)hv[2];
        a3 += (float)hv[3]; a4 += (float)hv[4];
    }
#pragma unroll
    for (int off = 1; off < 16; off <<= 1) {
        a0 += __shfl_xor(a0, off, 16);
        a1 += __shfl_xor(a1, off, 16);
        a2 += __shfl_xor(a2, off, 16);
        a3 += __shfl_xor(a3, off, 16);
        a4 += __shfl_xor(a4, off, 16);
    }
    if (lane == 0) {
        half8 gi = g1[node];
        float d = (float)gi[5];
        float v[FIN];
        v[0] = (a0 + (float)gi[0]) * d;
        v[1] = (a1 + (float)gi[1]) * d;
        v[2] = (a2 + (float)gi[2]) * d;
        v[3] = (a3 + (float)gi[3]) * d;
        v[4] = (a4 + (float)gi[4]) * d;
        half8 go = {};
#pragma unroll
        for (int j = 0; j < FHID; ++j) {
            float s = b1[j];
#pragma unroll
            for (int k = 0; k < FIN; ++k) s = fmaf(v[k], W1[k * FHID + j], s);
            go[j] = (_Float16)(fmaxf(s, 0.0f) * d);  // relu, pre-scaled
        }
        go[5] = gi[5];
        g2[node] = go;
    }
}

__global__ void k_vagg2(const unsigned int* __restrict__ ed,
                        const int* __restrict__ nodeptr,
                        const half8* __restrict__ g2,
                        const float* __restrict__ W2, const float* __restrict__ b2,
                        float* __restrict__ out, int n) {
    int tid = blockIdx.x * blockDim.x + threadIdx.x;
    int node = tid >> 4;
    int lane = tid & 15;
    if (node >= n) return;
    int o0 = nodeptr[node];
    int o1 = nodeptr[node + 1];
    float a0 = 0, a1 = 0, a2 = 0, a3 = 0, a4 = 0;
    for (int k = o0 + lane; k < o1; k += 16) {
        unsigned int s = __builtin_nontemporal_load(&ed[k]);
        half8 hv = g2[s];
        a0 += (float)hv[0]; a1 += (float)hv[1]; a2 += (float)hv[2];
        a3 += (float)hv[3]; a4 += (float)hv[4];
    }
#pragma unroll
    for (int off = 1; off < 16; off <<= 1) {
        a0 += __shfl_xor(a0, off, 16);
        a1 += __shfl_xor(a1, off, 16);
        a2 += __shfl_xor(a2, off, 16);
        a3 += __shfl_xor(a3, off, 16);
        a4 += __shfl_xor(a4, off, 16);
    }
    if (lane == 0) {
        half8 gi = g2[node];
        float d = (float)gi[5];
        float v[FHID];
        v[0] = (a0 + (float)gi[0]) * d;
        v[1] = (a1 + (float)gi[1]) * d;
        v[2] = (a2 + (float)gi[2]) * d;
        v[3] = (a3 + (float)gi[3]) * d;
        v[4] = (a4 + (float)gi[4]) * d;
        float o[FOUT];
        float m = -1e30f;
#pragma unroll
        for (int j = 0; j < FOUT; ++j) {
            float s = b2[j];
#pragma unroll
            for (int k = 0; k < FHID; ++k) s = fmaf(v[k], W2[k * FOUT + j], s);
            o[j] = s;
            m = fmaxf(m, s);
        }
        float ssum = 0.0f;
#pragma unroll
        for (int j = 0; j < FOUT; ++j) ssum += expf(o[j] - m);
        float lse = m + logf(ssum);
        float* op = out + (size_t)node * FOUT;
#pragma unroll
        for (int j = 0; j < FOUT; ++j) op[j] = o[j] - lse;
    }
}

// ---------------- fallback (R1 atomic path) ----------------

__global__ void f_init_deg(float* __restrict__ deg, int n) {
    int i = blockIdx.x * blockDim.x + threadIdx.x;
    if (i < n) deg[i] = 1.0f;
}
__global__ void f_count_deg(const int* __restrict__ dst, float* __restrict__ deg, int e) {
    int i = blockIdx.x * blockDim.x + threadIdx.x;
    if (i < e) atomicAdd(&deg[dst[i]], 1.0f);
}
__global__ void f_finish_deg_g1(const float* __restrict__ x, float* __restrict__ dinv,
                                float* __restrict__ g1, int n) {
    int i = blockIdx.x * blockDim.x + threadIdx.x;
    if (i >= n) return;
    float d = rsqrtf(dinv[i]);
    dinv[i] = d;
#pragma unroll
    for (int f = 0; f < FIN; ++f) g1[(size_t)i * FIN + f] = x[(size_t)i * FIN + f] * d;
}
__global__ void f_scatter5(const int* __restrict__ src, const int* __restrict__ dst,
                           const float* __restrict__ g, float* __restrict__ acc, int e) {
    int i = blockIdx.x * blockDim.x + threadIdx.x;
    if (i >= e) return;
    int s = src[i], d = dst[i];
    float* a = acc + (size_t)d * 5;
    const float* gp = g + (size_t)s * 5;
    atomicAdd(a + 0, gp[0]);
    atomicAdd(a + 1, gp[1]);
    atomicAdd(a + 2, gp[2]);
    atomicAdd(a + 3, gp[3]);
    atomicAdd(a + 4, gp[4]);
}
__global__ void f_update1(const float* __restrict__ dinv, float* __restrict__ g,
                          float* __restrict__ acc, const float* __restrict__ W1,
                          const float* __restrict__ b1, int n) {
    int i = blockIdx.x * blockDim.x + threadIdx.x;
    if (i >= n) return;
    float d = dinv[i];
    float v[FIN];
#pragma unroll
    for (int f = 0; f < FIN; ++f) {
        size_t idx = (size_t)i * FIN + f;
        v[f] = (acc[idx] + g[idx]) * d;
        acc[idx] = 0.0f;
    }
#pragma unroll
    for (int j = 0; j < FHID; ++j) {
        float s = b1[j];
#pragma unroll
        for (int k = 0; k < FIN; ++k) s += v[k] * W1[k * FHID + j];
        g[(size_t)i * FHID + j] = fmaxf(s, 0.0f) * d;
    }
}
__global__ void f_update2(const float* __restrict__ dinv, const float* __restrict__ g,
                          const float* __restrict__ acc, const float* __restrict__ W2,
                          const float* __restrict__ b2, float* __restrict__ out, int n) {
    int i = blockIdx.x * blockDim.x + threadIdx.x;
    if (i >= n) return;
    float d = dinv[i];
    float v[FHID];
#pragma unroll
    for (int f = 0; f < FHID; ++f) v[f] = (acc[(size_t)i * FHID + f] + g[(size_t)i * FHID + f]) * d;
    float o[FOUT];
    float m = -1e30f;
#pragma unroll
    for (int j = 0; j < FOUT; ++j) {
        float s = b2[j];
#pragma unroll
        for (int k = 0; k < FHID; ++k) s += v[k] * W2[k * FOUT + j];
        o[j] = s;
        m = fmaxf(m, s);
    }
    float ssum = 0.0f;
#pragma unroll
    for (int j = 0; j < FOUT; ++j) ssum += expf(o[j] - m);
    float lse = m + logf(ssum);
#pragma unroll
    for (int j = 0; j < FOUT; ++j) out[(size_t)i * FOUT + j] = o[j] - lse;
}

// ---------------- launcher ----------------

extern "C" void kernel_launch(void* const* d_in, const int* in_sizes, int n_in,
                              void* d_out, int out_size, void* d_ws, size_t ws_size,
                              hipStream_t stream) {
    const float* x  = (const float*)d_in[0];
    const int*   ei = (const int*)d_in[1];
    const float* W1 = (const float*)d_in[2];
    const float* b1 = (const float*)d_in[3];
    const float* W2 = (const float*)d_in[4];
    const float* b2 = (const float*)d_in[5];

    const int n = in_sizes[0] / FIN;   // 500,000
    const int e = in_sizes[1] / 2;     // 16,000,000
    const int* src = ei;
    const int* dst = ei + e;

    const int nbuck = (n + RB - 1) / RB;          // 1954
    const int nblkA = (e + EPA - 1) / EPA;        // 489
    const size_t m = (size_t)nbuck * nblkA;       // ~955k
    const int nsb = (int)((m + 255) / 256);

    size_t off = 0;
    auto al = [&](size_t bytes) { size_t o = off; off = (off + bytes + 15) & ~(size_t)15; return o; };
    int*          cnt     = (int*)((char*)d_ws + al(m * 4));
    int*          scn     = (int*)((char*)d_ws + al(m * 4));
    int*          part    = (int*)((char*)d_ws + al((size_t)nsb * 4));
    int*          nptr    = (int*)((char*)d_ws + al(((size_t)nbuck * RB + 1) * 4));
    half8*        g1      = (half8*)((char*)d_ws + al((size_t)n * 16));
    unsigned int* binnedA = (unsigned int*)((char*)d_ws + al((size_t)e * 4));
    unsigned int* binned3 = (unsigned int*)((char*)d_ws + al((size_t)e * 4));
    half8*        g2      = (half8*)binnedA;      // binnedA dead after passC
    const size_t need = off;

    if (ws_size >= need && n <= 524288 && n >= 1 && (e & 3) == 0 && nbuck <= NBUCK_MAX) {
        k_histA<<<nblkA, 1024, 0, stream>>>(dst, cnt, e, nbuck, nblkA);
        k_scan1<<<nsb, 256, 0, stream>>>(cnt, scn, part, (int)m);
        k_scan2<<<1, 256, 0, stream>>>(part, nsb);
        k_scatterA<<<nblkA, 1024, 0, stream>>>(src, dst, scn, part, binnedA, e, nbuck, nblkA);
        k_passC<<<nbuck, 512, 0, stream>>>(binnedA, scn, part, x, g1, binned3, nptr, n, e, nbuck, nblkA);
        const int ga = (int)(((size_t)n * 16 + 511) / 512);
        k_vagg1<<<ga, 512, 0, stream>>>(binned3, nptr, g1, W1, b1, g2, n);
        k_vagg2<<<ga, 512, 0, stream>>>(binned3, nptr, g2, W2, b2, (float*)d_out, n);
        return;
    }

    // R1 fallback (22 MB ws)
    const int B = 256;
    const int gn = (n + B - 1) / B;
    const int ge = (e + B - 1) / B;
    float* fdinv = (float*)d_ws;
    float* fg    = fdinv + n;
    float* facc  = fg + (size_t)5 * n;
    hipMemsetAsync(facc, 0, (size_t)5 * n * sizeof(float), stream);
    f_init_deg<<<gn, B, 0, stream>>>(fdinv, n);
    f_count_deg<<<ge, B, 0, stream>>>(dst, fdinv, e);
    f_finish_deg_g1<<<gn, B, 0, stream>>>(x, fdinv, fg, n);
    f_scatter5<<<ge, B, 0, stream>>>(src, dst, fg, facc, e);
    f_update1<<<gn, B, 0, stream>>>(fdinv, fg, facc, W1, b1, n);
    f_scatter5<<<ge, B, 0, stream>>>(src, dst, fg, facc, e);
    f_update2<<<gn, B, 0, stream>>>(fdinv, fg, facc, W2, b2, (float*)d_out, n);
}

// Round 10
// 509.616 us; speedup vs baseline: 3.2622x; 1.4398x over previous
//
#include <hip/hip_runtime.h>
#include <math.h>

// GCN 2-layer, N=500k, E=16M, F 5->5->8.
// R10: R9 + LDS-staged k_scatterA. R9 evidence: scattered global stores cost
//   ~12 cyc/edge w/ 6x write amplification (WRITE 405MB/64MB payload).
//   New scatterA: per-block LDS counting sort by bucket (hist -> in-place
//   2048-scan -> stage sorted into 96KB LDS -> flush 16-lanes-per-run,
//   runs written contiguously => full lines). LDS 120 KB/block.
// Pipeline: histA, scan, scatterA(LDS sort), passC(LDS node sort), vagg1/2.
// Fallback: R1 atomic-scatter path if ws/shape limits exceeded.

#define FIN 5
#define FHID 5
#define FOUT 8
#define RB 256        // nodes per bucket
#define EPA 24576     // edges per level-A block (96 KB staging)
#define NBUCK_MAX 2048
#define OCAP 10240    // passC LDS staging cap (mean 8188 + 22 sigma), 40 KB

typedef _Float16 half8 __attribute__((ext_vector_type(8)));
typedef int int4v __attribute__((ext_vector_type(4)));

// ---------------- scans ----------------

__global__ void k_scan1(const int* __restrict__ t, int* __restrict__ scn,
                        int* __restrict__ partial, int n) {
    __shared__ int sh[256];
    int tx = threadIdx.x;
    int i = blockIdx.x * 256 + tx;
    int v = (i < n) ? t[i] : 0;
    sh[tx] = v;
    __syncthreads();
    for (int off = 1; off < 256; off <<= 1) {
        int add = (tx >= off) ? sh[tx - off] : 0;
        __syncthreads();
        sh[tx] += add;
        __syncthreads();
    }
    if (i < n) scn[i] = sh[tx] - v;
    if (tx == 255) partial[blockIdx.x] = sh[255];
}

__global__ void k_scan2(int* __restrict__ partial, int nb) {
    __shared__ int sh[256];
    __shared__ int carry;
    int tx = threadIdx.x;
    if (tx == 0) carry = 0;
    __syncthreads();
    for (int base = 0; base < nb; base += 256) {
        int i = base + tx;
        int v = (i < nb) ? partial[i] : 0;
        int c0 = carry;
        sh[tx] = v;
        __syncthreads();
        for (int off = 1; off < 256; off <<= 1) {
            int add = (tx >= off) ? sh[tx - off] : 0;
            __syncthreads();
            sh[tx] += add;
            __syncthreads();
        }
        if (i < nb) partial[i] = c0 + sh[tx] - v;
        __syncthreads();
        if (tx == 0) carry = c0 + sh[255];
        __syncthreads();
    }
}

// ---------------- binning ----------------

__global__ void k_histA(const int* __restrict__ dst, int* __restrict__ cnt,
                        int e, int nbuck, int nblkA) {
    __shared__ int hist[NBUCK_MAX];
    int tx = threadIdx.x, blk = blockIdx.x;
    for (int b = tx; b < nbuck; b += 1024) hist[b] = 0;
    __syncthreads();
    size_t base = (size_t)blk * EPA;
    const int4v* dst4 = (const int4v*)dst;
    for (int k = 0; k < EPA / 4096; ++k) {
        size_t e4 = base / 4 + (size_t)k * 1024 + tx;
        size_t i = e4 * 4;
        if (i + 3 < (size_t)e) {
            int4v d4 = __builtin_nontemporal_load(&dst4[e4]);
#pragma unroll
            for (int j = 0; j < 4; ++j) atomicAdd(&hist[d4[j] >> 8], 1);
        } else {
            for (int j = 0; j < 4; ++j) {
                size_t ii = i + j;
                if (ii < (size_t)e) atomicAdd(&hist[dst[ii] >> 8], 1);
            }
        }
    }
    __syncthreads();
    for (int b = tx; b < nbuck; b += 1024) cnt[(size_t)b * nblkA + blk] = hist[b];
}

// LDS-staged scatter: local counting sort by bucket, coalesced run flush.
__global__ void k_scatterA(const int* __restrict__ src, const int* __restrict__ dst,
                           const int* __restrict__ scn, const int* __restrict__ part,
                           unsigned int* __restrict__ binnedA,
                           int e, int nbuck, int nblkA) {
    __shared__ int lstart[NBUCK_MAX];          // hist -> exclusive scan
    __shared__ int cur[NBUCK_MAX];
    __shared__ int gbase[NBUCK_MAX];
    __shared__ unsigned int staged[EPA];       // 96 KB
    int tx = threadIdx.x, blk = blockIdx.x;
    // init hist + load global cursor bases
    for (int b = tx; b < NBUCK_MAX; b += 1024) lstart[b] = 0;
    for (int b = tx; b < nbuck; b += 1024) {
        size_t idx = (size_t)b * nblkA + blk;
        gbase[b] = scn[idx] + part[idx >> 8];
    }
    __syncthreads();
    size_t base = (size_t)blk * EPA;
    const int4v* dst4 = (const int4v*)dst;
    const int4v* src4 = (const int4v*)src;
    // pass 1: local hist (plain loads; 2nd read below hits L2)
    for (int k = 0; k < EPA / 4096; ++k) {
        size_t e4 = base / 4 + (size_t)k * 1024 + tx;
        size_t i = e4 * 4;
        if (i + 3 < (size_t)e) {
            int4v d4 = dst4[e4];
#pragma unroll
            for (int j = 0; j < 4; ++j) atomicAdd(&lstart[d4[j] >> 8], 1);
        } else {
            for (int j = 0; j < 4; ++j) {
                size_t ii = i + j;
                if (ii < (size_t)e) atomicAdd(&lstart[dst[ii] >> 8], 1);
            }
        }
    }
    __syncthreads();
    // in-place inclusive scan of lstart[2048], 2 elems/thread,
    // reads complete before writes each step
    int j0 = tx, j1 = tx + 1024;
    int c0 = lstart[j0], c1 = lstart[j1];
    for (int off = 1; off < NBUCK_MAX; off <<= 1) {
        int a0 = (j0 >= off) ? lstart[j0 - off] : 0;
        int a1 = (j1 >= off) ? lstart[j1 - off] : 0;
        __syncthreads();
        lstart[j0] += a0; lstart[j1] += a1;
        __syncthreads();
    }
    // inclusive -> exclusive (keep counts in registers)
    int e0 = lstart[j0] - c0, e1 = lstart[j1] - c1;
    __syncthreads();
    lstart[j0] = e0; lstart[j1] = e1;
    cur[j0] = e0;    cur[j1] = e1;
    __syncthreads();
    // pass 2: stage sorted-by-bucket into LDS (scattered LDS writes ~free)
    for (int k = 0; k < EPA / 4096; ++k) {
        size_t e4 = base / 4 + (size_t)k * 1024 + tx;
        size_t i = e4 * 4;
        if (i + 3 < (size_t)e) {
            int4v d4 = dst4[e4];
            int4v s4 = src4[e4];
#pragma unroll
            for (int j = 0; j < 4; ++j) {
                int d = d4[j];
                int pos = atomicAdd(&cur[d >> 8], 1);
                staged[pos] = ((unsigned int)(d & (RB - 1)) << 19) | (unsigned int)s4[j];
            }
        } else {
            for (int j = 0; j < 4; ++j) {
                size_t ii = i + j;
                if (ii < (size_t)e) {
                    int d = dst[ii];
                    int pos = atomicAdd(&cur[d >> 8], 1);
                    staged[pos] = ((unsigned int)(d & (RB - 1)) << 19) | (unsigned int)src[ii];
                }
            }
        }
    }
    __syncthreads();
    // flush: 16 lanes per bucket-run -> contiguous global writes
    int grp = tx >> 4, lane = tx & 15;
    for (int b = grp; b < nbuck; b += 64) {
        int ls = lstart[b];
        int le = (b + 1 < NBUCK_MAX) ? lstart[b + 1] : 0;  // zeros beyond nbuck keep scan valid
        int cnt = le - ls;
        int gb = gbase[b];
        for (int k = lane; k < cnt; k += 16)
            binnedA[gb + k] = staged[ls + k];
    }
}

// ---------------- passC: LDS-staged node-sort + nodeptr + dinv + g1 ----------------

__global__ void k_passC(const unsigned int* __restrict__ binnedA,
                        const int* __restrict__ scn, const int* __restrict__ part,
                        const float* __restrict__ x,
                        half8* __restrict__ g1, unsigned int* __restrict__ binned3,
                        int* __restrict__ nodeptr,
                        int n, int e, int nbuck, int nblkA) {
    __shared__ int hist[RB];
    __shared__ int scanbuf[RB];
    __shared__ int cur[RB];
    __shared__ unsigned int obuf[OCAP];   // 40 KB
    int tx = threadIdx.x, b = blockIdx.x;
    if (tx < RB) hist[tx] = 0;
    __syncthreads();
    size_t i0 = (size_t)b * nblkA;
    int start = scn[i0] + part[i0 >> 8];
    int end;
    if (b + 1 < nbuck) {
        size_t i1 = (size_t)(b + 1) * nblkA;
        end = scn[i1] + part[i1 >> 8];
    } else {
        end = e;
    }
    int len = end - start;
    for (int i = start + tx; i < end; i += 512)
        atomicAdd(&hist[binnedA[i] >> 19], 1);
    __syncthreads();
    int v = 0;
    if (tx < RB) { v = hist[tx]; scanbuf[tx] = v; }
    __syncthreads();
    for (int off = 1; off < RB; off <<= 1) {
        int add = 0;
        if (tx < RB && tx >= off) add = scanbuf[tx - off];
        __syncthreads();
        if (tx < RB) scanbuf[tx] += add;
        __syncthreads();
    }
    if (tx < RB) {
        int excl = scanbuf[tx] - v;
        nodeptr[(size_t)b * RB + tx] = start + excl;
        cur[tx] = excl;
        int node = b * RB + tx;
        if (node < n) {
            float d = rsqrtf((float)(v + 1));   // +1 self-loop
            const float* xp = x + (size_t)node * FIN;
            half8 row = {};
#pragma unroll
            for (int f = 0; f < FIN; ++f) row[f] = (_Float16)(xp[f] * d);
            row[5] = (_Float16)d;               // dinv folded into slot 5
            g1[node] = row;
        }
    }
    if (b == nbuck - 1 && tx == 0) nodeptr[(size_t)nbuck * RB] = end;
    __syncthreads();
    if (len <= OCAP) {
        for (int i = start + tx; i < end; i += 512) {
            unsigned int p = binnedA[i];
            int pos = atomicAdd(&cur[p >> 19], 1);
            obuf[pos] = p & 0x7FFFFu;
        }
        __syncthreads();
        for (int j = tx; j < len; j += 512)
            binned3[start + j] = obuf[j];
    } else {
        for (int i = start + tx; i < end; i += 512) {
            unsigned int p = binnedA[i];
            int pos = atomicAdd(&cur[p >> 19], 1);
            binned3[start + pos] = p & 0x7FFFFu;
        }
    }
}

// ---------------- aggregation: 16 lanes/node, shfl reduce ----------------

__global__ void k_vagg1(const unsigned int* __restrict__ ed,
                        const int* __restrict__ nodeptr,
                        const half8* __restrict__ g1,
                        const float* __restrict__ W1, const float* __restrict__ b1,
                        half8* __restrict__ g2, int n) {
    int tid = blockIdx.x * blockDim.x + threadIdx.x;
    int node = tid >> 4;
    int lane = tid & 15;
    if (node >= n) return;
    int o0 = nodeptr[node];
    int o1 = nodeptr[node + 1];
    float a0 = 0, a1 = 0, a2 = 0, a3 = 0, a4 = 0;
    for (int k = o0 + lane; k < o1; k += 16) {
        unsigned int s = __builtin_nontemporal_load(&ed[k]);
        half8 hv = g1[s];
        a0 += (float)hv[0]; a1 += (float)hv[1]; a2 += (float)hv[2];
        a3 += (float)hv[3]; a4 += (float)hv[4];
    }
#pragma unroll
    for (int off = 1; off < 16; off <<= 1) {
        a0 += __shfl_xor(a0, off, 16);
        a1 += __shfl_xor(a1, off, 16);
        a2 += __shfl_xor(a2, off, 16);
        a3 += __shfl_xor(a3, off, 16);
        a4 += __shfl_xor(a4, off, 16);
    }
    if (lane == 0) {
        half8 gi = g1[node];
        float d = (float)gi[5];
        float v[FIN];
        v[0] = (a0 + (float)gi[0]) * d;
        v[1] = (a1 + (float)gi[1]) * d;
        v[2] = (a2 + (float)gi[2]) * d;
        v[3] = (a3 + (float)gi[3]) * d;
        v[4] = (a4 + (float)gi[4]) * d;
        half8 go = {};
#pragma unroll
        for (int j = 0; j < FHID; ++j) {
            float s = b1[j];
#pragma unroll
            for (int k = 0; k < FIN; ++k) s = fmaf(v[k], W1[k * FHID + j], s);
            go[j] = (_Float16)(fmaxf(s, 0.0f) * d);  // relu, pre-scaled
        }
        go[5] = gi[5];
        g2[node] = go;
    }
}

__global__ void k_vagg2(const unsigned int* __restrict__ ed,
                        const int* __restrict__ nodeptr,
                        const half8* __restrict__ g2,
                        const float* __restrict__ W2, const float* __restrict__ b2,
                        float* __restrict__ out, int n) {
    int tid = blockIdx.x * blockDim.x + threadIdx.x;
    int node = tid >> 4;
    int lane = tid & 15;
    if (node >= n) return;
    int o0 = nodeptr[node];
    int o1 = nodeptr[node + 1];
    float a0 = 0, a1 = 0, a2 = 0, a3 = 0, a4 = 0;
    for (int k = o0 + lane; k < o1; k += 16) {
        unsigned int s = __builtin_nontemporal_load(&ed[k]);
        half8 hv = g2[s];
        a0 += (float)hv[0]; a1 += (float)hv[1]; a2 += (float)hv[2];
        a3 += (float)hv[3]; a4 += (float)hv[4];
    }
#pragma unroll
    for (int off = 1; off < 16; off <<= 1) {
        a0 += __shfl_xor(a0, off, 16);
        a1 += __shfl_xor(a1, off, 16);
        a2 += __shfl_xor(a2, off, 16);
        a3 += __shfl_xor(a3, off, 16);
        a4 += __shfl_xor(a4, off, 16);
    }
    if (lane == 0) {
        half8 gi = g2[node];
        float d = (float)gi[5];
        float v[FHID];
        v[0] = (a0 + (float)gi[0]) * d;
        v[1] = (a1 + (float)gi[1]) * d;
        v[2] = (a2 + (float)gi[2]) * d;
        v[3] = (a3 + (float)gi[3]) * d;
        v[4] = (a4 + (float)gi[4]) * d;
        float o[FOUT];
        float m = -1e30f;
#pragma unroll
        for (int j = 0; j < FOUT; ++j) {
            float s = b2[j];
#pragma unroll
            for (int k = 0; k < FHID; ++k) s = fmaf(v[k], W2[k * FOUT + j], s);
            o[j] = s;
            m = fmaxf(m, s);
        }
        float ssum = 0.0f;
#pragma unroll
        for (int j = 0; j < FOUT; ++j) ssum += expf(o[j] - m);
        float lse = m + logf(ssum);
        float* op = out + (size_t)node * FOUT;
#pragma unroll
        for (int j = 0; j < FOUT; ++j) op[j] = o[j] - lse;
    }
}

// ---------------- fallback (R1 atomic path) ----------------

__global__ void f_init_deg(float* __restrict__ deg, int n) {
    int i = blockIdx.x * blockDim.x + threadIdx.x;
    if (i < n) deg[i] = 1.0f;
}
__global__ void f_count_deg(const int* __restrict__ dst, float* __restrict__ deg, int e) {
    int i = blockIdx.x * blockDim.x + threadIdx.x;
    if (i < e) atomicAdd(&deg[dst[i]], 1.0f);
}
__global__ void f_finish_deg_g1(const float* __restrict__ x, float* __restrict__ dinv,
                                float* __restrict__ g1, int n) {
    int i = blockIdx.x * blockDim.x + threadIdx.x;
    if (i >= n) return;
    float d = rsqrtf(dinv[i]);
    dinv[i] = d;
#pragma unroll
    for (int f = 0; f < FIN; ++f) g1[(size_t)i * FIN + f] = x[(size_t)i * FIN + f] * d;
}
__global__ void f_scatter5(const int* __restrict__ src, const int* __restrict__ dst,
                           const float* __restrict__ g, float* __restrict__ acc, int e) {
    int i = blockIdx.x * blockDim.x + threadIdx.x;
    if (i >= e) return;
    int s = src[i], d = dst[i];
    float* a = acc + (size_t)d * 5;
    const float* gp = g + (size_t)s * 5;
    atomicAdd(a + 0, gp[0]);
    atomicAdd(a + 1, gp[1]);
    atomicAdd(a + 2, gp[2]);
    atomicAdd(a + 3, gp[3]);
    atomicAdd(a + 4, gp[4]);
}
__global__ void f_update1(const float* __restrict__ dinv, float* __restrict__ g,
                          float* __restrict__ acc, const float* __restrict__ W1,
                          const float* __restrict__ b1, int n) {
    int i = blockIdx.x * blockDim.x + threadIdx.x;
    if (i >= n) return;
    float d = dinv[i];
    float v[FIN];
#pragma unroll
    for (int f = 0; f < FIN; ++f) {
        size_t idx = (size_t)i * FIN + f;
        v[f] = (acc[idx] + g[idx]) * d;
        acc[idx] = 0.0f;
    }
#pragma unroll
    for (int j = 0; j < FHID; ++j) {
        float s = b1[j];
#pragma unroll
        for (int k = 0; k < FIN; ++k) s += v[k] * W1[k * FHID + j];
        g[(size_t)i * FHID + j] = fmaxf(s, 0.0f) * d;
    }
}
__global__ void f_update2(const float* __restrict__ dinv, const float* __restrict__ g,
                          const float* __restrict__ acc, const float* __restrict__ W2,
                          const float* __restrict__ b2, float* __restrict__ out, int n) {
    int i = blockIdx.x * blockDim.x + threadIdx.x;
    if (i >= n) return;
    float d = dinv[i];
    float v[FHID];
#pragma unroll
    for (int f = 0; f < FHID; ++f) v[f] = (acc[(size_t)i * FHID + f] + g[(size_t)i * FHID + f]) * d;
    float o[FOUT];
    float m = -1e30f;
#pragma unroll
    for (int j = 0; j < FOUT; ++j) {
        float s = b2[j];
#pragma unroll
        for (int k = 0; k < FHID; ++k) s += v[k] * W2[k * FOUT + j];
        o[j] = s;
        m = fmaxf(m, s);
    }
    float ssum = 0.0f;
#pragma unroll
    for (int j = 0; j < FOUT; ++j) ssum += expf(o[j] - m);
    float lse = m + logf(ssum);
#pragma unroll
    for (int j = 0; j < FOUT; ++j) out[(size_t)i * FOUT + j] = o[j] - lse;
}

// ---------------- launcher ----------------

extern "C" void kernel_launch(void* const* d_in, const int* in_sizes, int n_in,
                              void* d_out, int out_size, void* d_ws, size_t ws_size,
                              hipStream_t stream) {
    const float* x  = (const float*)d_in[0];
    const int*   ei = (const int*)d_in[1];
    const float* W1 = (const float*)d_in[2];
    const float* b1 = (const float*)d_in[3];
    const float* W2 = (const float*)d_in[4];
    const float* b2 = (const float*)d_in[5];

    const int n = in_sizes[0] / FIN;   // 500,000
    const int e = in_sizes[1] / 2;     // 16,000,000
    const int* src = ei;
    const int* dst = ei + e;

    const int nbuck = (n + RB - 1) / RB;          // 1954
    const int nblkA = (e + EPA - 1) / EPA;        // 652
    const size_t m = (size_t)nbuck * nblkA;       // ~1.27M
    const int nsb = (int)((m + 255) / 256);

    size_t off = 0;
    auto al = [&](size_t bytes) { size_t o = off; off = (off + bytes + 15) & ~(size_t)15; return o; };
    int*          cnt     = (int*)((char*)d_ws + al(m * 4));
    int*          scn     = (int*)((char*)d_ws + al(m * 4));
    int*          part    = (int*)((char*)d_ws + al((size_t)nsb * 4));
    int*          nptr    = (int*)((char*)d_ws + al(((size_t)nbuck * RB + 1) * 4));
    half8*        g1      = (half8*)((char*)d_ws + al((size_t)n * 16));
    unsigned int* binnedA = (unsigned int*)((char*)d_ws + al((size_t)e * 4));
    unsigned int* binned3 = (unsigned int*)((char*)d_ws + al((size_t)e * 4));
    half8*        g2      = (half8*)binnedA;      // binnedA dead after passC
    const size_t need = off;

    if (ws_size >= need && n <= 524288 && n >= 1 && (e & 3) == 0 && nbuck <= NBUCK_MAX) {
        k_histA<<<nblkA, 1024, 0, stream>>>(dst, cnt, e, nbuck, nblkA);
        k_scan1<<<nsb, 256, 0, stream>>>(cnt, scn, part, (int)m);
        k_scan2<<<1, 256, 0, stream>>>(part, nsb);
        k_scatterA<<<nblkA, 1024, 0, stream>>>(src, dst, scn, part, binnedA, e, nbuck, nblkA);
        k_passC<<<nbuck, 512, 0, stream>>>(binnedA, scn, part, x, g1, binned3, nptr, n, e, nbuck, nblkA);
        const int ga = (int)(((size_t)n * 16 + 511) / 512);
        k_vagg1<<<ga, 512, 0, stream>>>(binned3, nptr, g1, W1, b1, g2, n);
        k_vagg2<<<ga, 512, 0, stream>>>(binned3, nptr, g2, W2, b2, (float*)d_out, n);
        return;
    }

    // R1 fallback (22 MB ws)
    const int B = 256;
    const int gn = (n + B - 1) / B;
    const int ge = (e + B - 1) / B;
    float* fdinv = (float*)d_ws;
    float* fg    = fdinv + n;
    float* facc  = fg + (size_t)5 * n;
    hipMemsetAsync(facc, 0, (size_t)5 * n * sizeof(float), stream);
    f_init_deg<<<gn, B, 0, stream>>>(fdinv, n);
    f_count_deg<<<ge, B, 0, stream>>>(dst, fdinv, e);
    f_finish_deg_g1<<<gn, B, 0, stream>>>(x, fdinv, fg, n);
    f_scatter5<<<ge, B, 0, stream>>>(src, dst, fg, facc, e);
    f_update1<<<gn, B, 0, stream>>>(fdinv, fg, facc, W1, b1, n);
    f_scatter5<<<ge, B, 0, stream>>>(src, dst, fg, facc, e);
    f_update2<<<gn, B, 0, stream>>>(fdinv, fg, facc, W2, b2, (float*)d_out, n);
}

// Round 12
// 489.793 us; speedup vs baseline: 3.3942x; 1.0405x over previous
//
#include <hip/hip_runtime.h>
#include <math.h>

// GCN 2-layer, N=500k, E=16M, F 5->5->8.
// R11b: R10 + (a) src-phase split: passC sorts each node's list with key
//   (dl<<1 | src>=n/2) and emits midptr; each vagg layer runs as two
//   launches whose gather working set is a 4 MB half-table (per-XCD-L2
//   resident). f32 partials carried in acc4/acc1 (aliased into dead
//   binnedA space). (b) scatterA's local hist pass deleted -- it equals
//   cnt[b][blk] from histA; loaded instead of recomputed.
//   (fix vs R11: ext_vector fl4 for nontemporal float4 store)
// Fallback: R1 atomic-scatter path if ws/shape limits exceeded.

#define FIN 5
#define FHID 5
#define FOUT 8
#define RB 256        // nodes per bucket
#define EPA 24576     // edges per level-A block (96 KB staging)
#define NBUCK_MAX 2048
#define OCAP 10240    // passC LDS staging cap (mean 8188 + 22 sigma), 40 KB

typedef _Float16 half8 __attribute__((ext_vector_type(8)));
typedef int int4v __attribute__((ext_vector_type(4)));
typedef float fl4 __attribute__((ext_vector_type(4)));

// ---------------- scans ----------------

__global__ void k_scan1(const int* __restrict__ t, int* __restrict__ scn,
                        int* __restrict__ partial, int n) {
    __shared__ int sh[256];
    int tx = threadIdx.x;
    int i = blockIdx.x * 256 + tx;
    int v = (i < n) ? t[i] : 0;
    sh[tx] = v;
    __syncthreads();
    for (int off = 1; off < 256; off <<= 1) {
        int add = (tx >= off) ? sh[tx - off] : 0;
        __syncthreads();
        sh[tx] += add;
        __syncthreads();
    }
    if (i < n) scn[i] = sh[tx] - v;
    if (tx == 255) partial[blockIdx.x] = sh[255];
}

__global__ void k_scan2(int* __restrict__ partial, int nb) {
    __shared__ int sh[256];
    __shared__ int carry;
    int tx = threadIdx.x;
    if (tx == 0) carry = 0;
    __syncthreads();
    for (int base = 0; base < nb; base += 256) {
        int i = base + tx;
        int v = (i < nb) ? partial[i] : 0;
        int c0 = carry;
        sh[tx] = v;
        __syncthreads();
        for (int off = 1; off < 256; off <<= 1) {
            int add = (tx >= off) ? sh[tx - off] : 0;
            __syncthreads();
            sh[tx] += add;
            __syncthreads();
        }
        if (i < nb) partial[i] = c0 + sh[tx] - v;
        __syncthreads();
        if (tx == 0) carry = c0 + sh[255];
        __syncthreads();
    }
}

// ---------------- binning ----------------

__global__ void k_histA(const int* __restrict__ dst, int* __restrict__ cnt,
                        int e, int nbuck, int nblkA) {
    __shared__ int hist[NBUCK_MAX];
    int tx = threadIdx.x, blk = blockIdx.x;
    for (int b = tx; b < nbuck; b += 1024) hist[b] = 0;
    __syncthreads();
    size_t base = (size_t)blk * EPA;
    const int4v* dst4 = (const int4v*)dst;
    for (int k = 0; k < EPA / 4096; ++k) {
        size_t e4 = base / 4 + (size_t)k * 1024 + tx;
        size_t i = e4 * 4;
        if (i + 3 < (size_t)e) {
            int4v d4 = __builtin_nontemporal_load(&dst4[e4]);
#pragma unroll
            for (int j = 0; j < 4; ++j) atomicAdd(&hist[d4[j] >> 8], 1);
        } else {
            for (int j = 0; j < 4; ++j) {
                size_t ii = i + j;
                if (ii < (size_t)e) atomicAdd(&hist[dst[ii] >> 8], 1);
            }
        }
    }
    __syncthreads();
    for (int b = tx; b < nbuck; b += 1024) cnt[(size_t)b * nblkA + blk] = hist[b];
}

// LDS-staged scatter: local hist LOADED from cnt (histA already computed it),
// scan -> stage sorted-by-bucket into LDS -> coalesced run flush.
__global__ void k_scatterA(const int* __restrict__ src, const int* __restrict__ dst,
                           const int* __restrict__ cnt,
                           const int* __restrict__ scn, const int* __restrict__ part,
                           unsigned int* __restrict__ binnedA,
                           int e, int nbuck, int nblkA) {
    __shared__ int lstart[NBUCK_MAX];          // local counts -> exclusive scan
    __shared__ int cur[NBUCK_MAX];
    __shared__ int gbase[NBUCK_MAX];
    __shared__ unsigned int staged[EPA];       // 96 KB
    int tx = threadIdx.x, blk = blockIdx.x;
    for (int b = tx; b < NBUCK_MAX; b += 1024) {
        if (b < nbuck) {
            size_t idx = (size_t)b * nblkA + blk;
            lstart[b] = cnt[idx];
            gbase[b] = scn[idx] + part[idx >> 8];
        } else {
            lstart[b] = 0;
        }
    }
    __syncthreads();
    // in-place inclusive scan of lstart[2048], 2 elems/thread
    int j0 = tx, j1 = tx + 1024;
    int c0 = lstart[j0], c1 = lstart[j1];
    for (int off = 1; off < NBUCK_MAX; off <<= 1) {
        int a0 = (j0 >= off) ? lstart[j0 - off] : 0;
        int a1 = (j1 >= off) ? lstart[j1 - off] : 0;
        __syncthreads();
        lstart[j0] += a0; lstart[j1] += a1;
        __syncthreads();
    }
    int e0 = lstart[j0] - c0, e1 = lstart[j1] - c1;
    __syncthreads();
    lstart[j0] = e0; lstart[j1] = e1;
    cur[j0] = e0;    cur[j1] = e1;
    __syncthreads();
    // stage sorted-by-bucket into LDS (scattered LDS writes ~free)
    size_t base = (size_t)blk * EPA;
    const int4v* dst4 = (const int4v*)dst;
    const int4v* src4 = (const int4v*)src;
    for (int k = 0; k < EPA / 4096; ++k) {
        size_t e4 = base / 4 + (size_t)k * 1024 + tx;
        size_t i = e4 * 4;
        if (i + 3 < (size_t)e) {
            int4v d4 = __builtin_nontemporal_load(&dst4[e4]);
            int4v s4 = __builtin_nontemporal_load(&src4[e4]);
#pragma unroll
            for (int j = 0; j < 4; ++j) {
                int d = d4[j];
                int pos = atomicAdd(&cur[d >> 8], 1);
                staged[pos] = ((unsigned int)(d & (RB - 1)) << 19) | (unsigned int)s4[j];
            }
        } else {
            for (int j = 0; j < 4; ++j) {
                size_t ii = i + j;
                if (ii < (size_t)e) {
                    int d = dst[ii];
                    int pos = atomicAdd(&cur[d >> 8], 1);
                    staged[pos] = ((unsigned int)(d & (RB - 1)) << 19) | (unsigned int)src[ii];
                }
            }
        }
    }
    __syncthreads();
    // flush: 16 lanes per bucket-run -> contiguous global writes
    int grp = tx >> 4, lane = tx & 15;
    for (int b = grp; b < nbuck; b += 64) {
        int ls = lstart[b];
        int le = (b + 1 < NBUCK_MAX) ? lstart[b + 1] : 0;
        int len = le - ls;
        int gb = gbase[b];
        for (int k = lane; k < len; k += 16)
            binnedA[gb + k] = staged[ls + k];
    }
}

// ---------------- passC: 512-bin (node, src-phase) sort + nodeptr/midptr + g1 ----------------

__global__ void k_passC(const unsigned int* __restrict__ binnedA,
                        const int* __restrict__ scn, const int* __restrict__ part,
                        const float* __restrict__ x,
                        half8* __restrict__ g1, unsigned int* __restrict__ binned3,
                        int* __restrict__ nodeptr, int* __restrict__ midptr,
                        int n, int e, int nbuck, int nblkA, unsigned int half) {
    __shared__ int hist[2 * RB];       // 512 bins: (dl<<1)|phase
    __shared__ int scanbuf[2 * RB];
    __shared__ int cur[2 * RB];
    __shared__ unsigned int obuf[OCAP];   // 40 KB
    int tx = threadIdx.x, b = blockIdx.x;  // blockDim 512
    hist[tx] = 0;
    __syncthreads();
    size_t i0 = (size_t)b * nblkA;
    int start = scn[i0] + part[i0 >> 8];
    int end;
    if (b + 1 < nbuck) {
        size_t i1 = (size_t)(b + 1) * nblkA;
        end = scn[i1] + part[i1 >> 8];
    } else {
        end = e;
    }
    int len = end - start;
    for (int i = start + tx; i < end; i += 512) {
        unsigned int p = binnedA[i];
        int key = (int)((p >> 19) << 1) | ((p & 0x7FFFFu) >= half ? 1 : 0);
        atomicAdd(&hist[key], 1);
    }
    __syncthreads();
    int v = hist[tx];
    scanbuf[tx] = v;
    __syncthreads();
    for (int off = 1; off < 2 * RB; off <<= 1) {
        int add = (tx >= off) ? scanbuf[tx - off] : 0;
        __syncthreads();
        scanbuf[tx] += add;
        __syncthreads();
    }
    int excl = scanbuf[tx] - v;
    cur[tx] = excl;
    if ((tx & 1) == 0) nodeptr[(size_t)b * RB + (tx >> 1)] = start + excl;
    else               midptr[(size_t)b * RB + (tx >> 1)]  = start + excl;
    if (tx < RB) {
        int node = b * RB + tx;
        if (node < n) {
            int deg = hist[2 * tx] + hist[2 * tx + 1];
            float d = rsqrtf((float)(deg + 1));  // +1 self-loop
            const float* xp = x + (size_t)node * FIN;
            half8 row = {};
#pragma unroll
            for (int f = 0; f < FIN; ++f) row[f] = (_Float16)(xp[f] * d);
            row[5] = (_Float16)d;                // dinv folded into slot 5
            g1[node] = row;
        }
    }
    if (b == nbuck - 1 && tx == 0) nodeptr[(size_t)nbuck * RB] = end;
    __syncthreads();
    if (len <= OCAP) {
        for (int i = start + tx; i < end; i += 512) {
            unsigned int p = binnedA[i];
            int key = (int)((p >> 19) << 1) | ((p & 0x7FFFFu) >= half ? 1 : 0);
            int pos = atomicAdd(&cur[key], 1);
            obuf[pos] = p & 0x7FFFFu;
        }
        __syncthreads();
        for (int j = tx; j < len; j += 512)
            binned3[start + j] = obuf[j];
    } else {
        for (int i = start + tx; i < end; i += 512) {
            unsigned int p = binnedA[i];
            int key = (int)((p >> 19) << 1) | ((p & 0x7FFFFu) >= half ? 1 : 0);
            int pos = atomicAdd(&cur[key], 1);
            binned3[start + pos] = p & 0x7FFFFu;
        }
    }
}

// ---------------- aggregation: phase-split, 16 lanes/node ----------------

// phase 0 (src < half): gather half-table (L2-resident), store f32 partials
__global__ void k_vphase0(const unsigned int* __restrict__ ed,
                          const int* __restrict__ nodeptr, const int* __restrict__ midptr,
                          const half8* __restrict__ g,
                          fl4* __restrict__ acc4, float* __restrict__ acc1, int n) {
    int tid = blockIdx.x * blockDim.x + threadIdx.x;
    int node = tid >> 4;
    int lane = tid & 15;
    if (node >= n) return;
    int o0 = nodeptr[node];
    int om = midptr[node];
    float a0 = 0, a1 = 0, a2 = 0, a3 = 0, a4 = 0;
    for (int k = o0 + lane; k < om; k += 16) {
        unsigned int s = __builtin_nontemporal_load(&ed[k]);
        half8 hv = g[s];
        a0 += (float)hv[0]; a1 += (float)hv[1]; a2 += (float)hv[2];
        a3 += (float)hv[3]; a4 += (float)hv[4];
    }
#pragma unroll
    for (int off = 1; off < 16; off <<= 1) {
        a0 += __shfl_xor(a0, off, 16);
        a1 += __shfl_xor(a1, off, 16);
        a2 += __shfl_xor(a2, off, 16);
        a3 += __shfl_xor(a3, off, 16);
        a4 += __shfl_xor(a4, off, 16);
    }
    if (lane == 0) {
        fl4 p; p.x = a0; p.y = a1; p.z = a2; p.w = a3;
        __builtin_nontemporal_store(p, &acc4[node]);
        __builtin_nontemporal_store(a4, &acc1[node]);
    }
}

// phase 1 layer 1 (src >= half): add partials + self, W1+relu epilogue
__global__ void k_vp1_l1(const unsigned int* __restrict__ ed,
                         const int* __restrict__ nodeptr, const int* __restrict__ midptr,
                         const half8* __restrict__ g1,
                         const fl4* __restrict__ acc4, const float* __restrict__ acc1,
                         const float* __restrict__ W1, const float* __restrict__ b1,
                         half8* __restrict__ g2, int n) {
    int tid = blockIdx.x * blockDim.x + threadIdx.x;
    int node = tid >> 4;
    int lane = tid & 15;
    if (node >= n) return;
    int om = midptr[node];
    int o1 = nodeptr[node + 1];
    float a0 = 0, a1 = 0, a2 = 0, a3 = 0, a4 = 0;
    for (int k = om + lane; k < o1; k += 16) {
        unsigned int s = __builtin_nontemporal_load(&ed[k]);
        half8 hv = g1[s];
        a0 += (float)hv[0]; a1 += (float)hv[1]; a2 += (float)hv[2];
        a3 += (float)hv[3]; a4 += (float)hv[4];
    }
#pragma unroll
    for (int off = 1; off < 16; off <<= 1) {
        a0 += __shfl_xor(a0, off, 16);
        a1 += __shfl_xor(a1, off, 16);
        a2 += __shfl_xor(a2, off, 16);
        a3 += __shfl_xor(a3, off, 16);
        a4 += __shfl_xor(a4, off, 16);
    }
    if (lane == 0) {
        fl4 pp = acc4[node];
        float p4 = acc1[node];
        half8 gi = g1[node];
        float d = (float)gi[5];
        float v[FIN];
        v[0] = (a0 + pp.x + (float)gi[0]) * d;
        v[1] = (a1 + pp.y + (float)gi[1]) * d;
        v[2] = (a2 + pp.z + (float)gi[2]) * d;
        v[3] = (a3 + pp.w + (float)gi[3]) * d;
        v[4] = (a4 + p4   + (float)gi[4]) * d;
        half8 go = {};
#pragma unroll
        for (int j = 0; j < FHID; ++j) {
            float s = b1[j];
#pragma unroll
            for (int k = 0; k < FIN; ++k) s = fmaf(v[k], W1[k * FHID + j], s);
            go[j] = (_Float16)(fmaxf(s, 0.0f) * d);  // relu, pre-scaled
        }
        go[5] = gi[5];
        g2[node] = go;
    }
}

// phase 1 layer 2: add partials + self, W2 + log_softmax epilogue
__global__ void k_vp1_l2(const unsigned int* __restrict__ ed,
                         const int* __restrict__ nodeptr, const int* __restrict__ midptr,
                         const half8* __restrict__ g2,
                         const fl4* __restrict__ acc4, const float* __restrict__ acc1,
                         const float* __restrict__ W2, const float* __restrict__ b2,
                         float* __restrict__ out, int n) {
    int tid = blockIdx.x * blockDim.x + threadIdx.x;
    int node = tid >> 4;
    int lane = tid & 15;
    if (node >= n) return;
    int om = midptr[node];
    int o1 = nodeptr[node + 1];
    float a0 = 0, a1 = 0, a2 = 0, a3 = 0, a4 = 0;
    for (int k = om + lane; k < o1; k += 16) {
        unsigned int s = __builtin_nontemporal_load(&ed[k]);
        half8 hv = g2[s];
        a0 += (float)hv[0]; a1 += (float)hv[1]; a2 += (float)hv[2];
        a3 += (float)hv[3]; a4 += (float)hv[4];
    }
#pragma unroll
    for (int off = 1; off < 16; off <<= 1) {
        a0 += __shfl_xor(a0, off, 16);
        a1 += __shfl_xor(a1, off, 16);
        a2 += __shfl_xor(a2, off, 16);
        a3 += __shfl_xor(a3, off, 16);
        a4 += __shfl_xor(a4, off, 16);
    }
    if (lane == 0) {
        fl4 pp = acc4[node];
        float p4 = acc1[node];
        half8 gi = g2[node];
        float d = (float)gi[5];
        float v[FHID];
        v[0] = (a0 + pp.x + (float)gi[0]) * d;
        v[1] = (a1 + pp.y + (float)gi[1]) * d;
        v[2] = (a2 + pp.z + (float)gi[2]) * d;
        v[3] = (a3 + pp.w + (float)gi[3]) * d;
        v[4] = (a4 + p4   + (float)gi[4]) * d;
        float o[FOUT];
        float m = -1e30f;
#pragma unroll
        for (int j = 0; j < FOUT; ++j) {
            float s = b2[j];
#pragma unroll
            for (int k = 0; k < FHID; ++k) s = fmaf(v[k], W2[k * FOUT + j], s);
            o[j] = s;
            m = fmaxf(m, s);
        }
        float ssum = 0.0f;
#pragma unroll
        for (int j = 0; j < FOUT; ++j) ssum += expf(o[j] - m);
        float lse = m + logf(ssum);
        float* op = out + (size_t)node * FOUT;
#pragma unroll
        for (int j = 0; j < FOUT; ++j) op[j] = o[j] - lse;
    }
}

// ---------------- fallback (R1 atomic path) ----------------

__global__ void f_init_deg(float* __restrict__ deg, int n) {
    int i = blockIdx.x * blockDim.x + threadIdx.x;
    if (i < n) deg[i] = 1.0f;
}
__global__ void f_count_deg(const int* __restrict__ dst, float* __restrict__ deg, int e) {
    int i = blockIdx.x * blockDim.x + threadIdx.x;
    if (i < e) atomicAdd(&deg[dst[i]], 1.0f);
}
__global__ void f_finish_deg_g1(const float* __restrict__ x, float* __restrict__ dinv,
                                float* __restrict__ g1, int n) {
    int i = blockIdx.x * blockDim.x + threadIdx.x;
    if (i >= n) return;
    float d = rsqrtf(dinv[i]);
    dinv[i] = d;
#pragma unroll
    for (int f = 0; f < FIN; ++f) g1[(size_t)i * FIN + f] = x[(size_t)i * FIN + f] * d;
}
__global__ void f_scatter5(const int* __restrict__ src, const int* __restrict__ dst,
                           const float* __restrict__ g, float* __restrict__ acc, int e) {
    int i = blockIdx.x * blockDim.x + threadIdx.x;
    if (i >= e) return;
    int s = src[i], d = dst[i];
    float* a = acc + (size_t)d * 5;
    const float* gp = g + (size_t)s * 5;
    atomicAdd(a + 0, gp[0]);
    atomicAdd(a + 1, gp[1]);
    atomicAdd(a + 2, gp[2]);
    atomicAdd(a + 3, gp[3]);
    atomicAdd(a + 4, gp[4]);
}
__global__ void f_update1(const float* __restrict__ dinv, float* __restrict__ g,
                          float* __restrict__ acc, const float* __restrict__ W1,
                          const float* __restrict__ b1, int n) {
    int i = blockIdx.x * blockDim.x + threadIdx.x;
    if (i >= n) return;
    float d = dinv[i];
    float v[FIN];
#pragma unroll
    for (int f = 0; f < FIN; ++f) {
        size_t idx = (size_t)i * FIN + f;
        v[f] = (acc[idx] + g[idx]) * d;
        acc[idx] = 0.0f;
    }
#pragma unroll
    for (int j = 0; j < FHID; ++j) {
        float s = b1[j];
#pragma unroll
        for (int k = 0; k < FIN; ++k) s += v[k] * W1[k * FHID + j];
        g[(size_t)i * FHID + j] = fmaxf(s, 0.0f) * d;
    }
}
__global__ void f_update2(const float* __restrict__ dinv, const float* __restrict__ g,
                          const float* __restrict__ acc, const float* __restrict__ W2,
                          const float* __restrict__ b2, float* __restrict__ out, int n) {
    int i = blockIdx.x * blockDim.x + threadIdx.x;
    if (i >= n) return;
    float d = dinv[i];
    float v[FHID];
#pragma unroll
    for (int f = 0; f < FHID; ++f) v[f] = (acc[(size_t)i * FHID + f] + g[(size_t)i * FHID + f]) * d;
    float o[FOUT];
    float m = -1e30f;
#pragma unroll
    for (int j = 0; j < FOUT; ++j) {
        float s = b2[j];
#pragma unroll
        for (int k = 0; k < FHID; ++k) s += v[k] * W2[k * FOUT + j];
        o[j] = s;
        m = fmaxf(m, s);
    }
    float ssum = 0.0f;
#pragma unroll
    for (int j = 0; j < FOUT; ++j) ssum += expf(o[j] - m);
    float lse = m + logf(ssum);
#pragma unroll
    for (int j = 0; j < FOUT; ++j) out[(size_t)i * FOUT + j] = o[j] - lse;
}

// ---------------- launcher ----------------

extern "C" void kernel_launch(void* const* d_in, const int* in_sizes, int n_in,
                              void* d_out, int out_size, void* d_ws, size_t ws_size,
                              hipStream_t stream) {
    const float* x  = (const float*)d_in[0];
    const int*   ei = (const int*)d_in[1];
    const float* W1 = (const float*)d_in[2];
    const float* b1 = (const float*)d_in[3];
    const float* W2 = (const float*)d_in[4];
    const float* b2 = (const float*)d_in[5];

    const int n = in_sizes[0] / FIN;   // 500,000
    const int e = in_sizes[1] / 2;     // 16,000,000
    const int* src = ei;
    const int* dst = ei + e;

    const int nbuck = (n + RB - 1) / RB;          // 1954
    const int nblkA = (e + EPA - 1) / EPA;        // 652
    const size_t m = (size_t)nbuck * nblkA;       // ~1.27M
    const int nsb = (int)((m + 255) / 256);

    size_t off = 0;
    auto al = [&](size_t bytes) { size_t o = off; off = (off + bytes + 15) & ~(size_t)15; return o; };
    int*          cnt     = (int*)((char*)d_ws + al(m * 4));
    int*          scn     = (int*)((char*)d_ws + al(m * 4));
    int*          part    = (int*)((char*)d_ws + al((size_t)nsb * 4));
    int*          nptr    = (int*)((char*)d_ws + al(((size_t)nbuck * RB + 1) * 4));
    int*          mptr    = (int*)((char*)d_ws + al((size_t)nbuck * RB * 4));
    half8*        g1      = (half8*)((char*)d_ws + al((size_t)n * 16));
    unsigned int* binnedA = (unsigned int*)((char*)d_ws + al((size_t)e * 4));
    unsigned int* binned3 = (unsigned int*)((char*)d_ws + al((size_t)e * 4));
    // binnedA (64 MB) is dead after passC -- carve post-sort buffers from it:
    half8*        g2      = (half8*)binnedA;                          // 8 MB @ 0
    fl4*          acc4    = (fl4*)((char*)binnedA + (size_t)16 * 1024 * 1024);   // 8 MB @ 16M
    float*        acc1    = (float*)((char*)binnedA + (size_t)32 * 1024 * 1024); // 2 MB @ 32M
    const size_t need = off;

    if (ws_size >= need && n <= 524288 && n >= 1 && (e & 3) == 0 && nbuck <= NBUCK_MAX &&
        (size_t)e * 4 >= (size_t)34 * 1024 * 1024 && (size_t)n * 16 <= (size_t)16 * 1024 * 1024) {
        const unsigned int half = (unsigned int)(n >> 1);
        k_histA<<<nblkA, 1024, 0, stream>>>(dst, cnt, e, nbuck, nblkA);
        k_scan1<<<nsb, 256, 0, stream>>>(cnt, scn, part, (int)m);
        k_scan2<<<1, 256, 0, stream>>>(part, nsb);
        k_scatterA<<<nblkA, 1024, 0, stream>>>(src, dst, cnt, scn, part, binnedA, e, nbuck, nblkA);
        k_passC<<<nbuck, 512, 0, stream>>>(binnedA, scn, part, x, g1, binned3, nptr, mptr,
                                           n, e, nbuck, nblkA, half);
        const int ga = (int)(((size_t)n * 16 + 511) / 512);
        k_vphase0<<<ga, 512, 0, stream>>>(binned3, nptr, mptr, g1, acc4, acc1, n);
        k_vp1_l1<<<ga, 512, 0, stream>>>(binned3, nptr, mptr, g1, acc4, acc1, W1, b1, g2, n);
        k_vphase0<<<ga, 512, 0, stream>>>(binned3, nptr, mptr, g2, acc4, acc1, n);
        k_vp1_l2<<<ga, 512, 0, stream>>>(binned3, nptr, mptr, g2, acc4, acc1, W2, b2, (float*)d_out, n);
        return;
    }

    // R1 fallback (22 MB ws)
    const int B = 256;
    const int gn = (n + B - 1) / B;
    const int ge = (e + B - 1) / B;
    float* fdinv = (float*)d_ws;
    float* fg    = fdinv + n;
    float* facc  = fg + (size_t)5 * n;
    hipMemsetAsync(facc, 0, (size_t)5 * n * sizeof(float), stream);
    f_init_deg<<<gn, B, 0, stream>>>(fdinv, n);
    f_count_deg<<<ge, B, 0, stream>>>(dst, fdinv, e);
    f_finish_deg_g1<<<gn, B, 0, stream>>>(x, fdinv, fg, n);
    f_scatter5<<<ge, B, 0, stream>>>(src, dst, fg, facc, e);
    f_update1<<<gn, B, 0, stream>>>(fdinv, fg, facc, W1, b1, n);
    f_scatter5<<<ge, B, 0, stream>>>(src, dst, fg, facc, e);
    f_update2<<<gn, B, 0, stream>>>(fdinv, fg, facc, W2, b2, (float*)d_out, n);
}